// Round 12
// baseline (463.719 us; speedup 1.0000x reference)
//
#include <hip/hip_runtime.h>

#define NN 50000
#define NE 800000
#define DD 128
#define DQ 64
#define NB 84          // histogram/fill blocks per (relation, array)
#define SL 9524        // edge slice per block: 84*9524 = 800016 >= NE
#define NWW 12500      // packed uint8x4 words covering NN counters

typedef __attribute__((ext_vector_type(8))) short short8_t;  // 8 bf16 (4 VGPR)
typedef __attribute__((ext_vector_type(4))) float f32x4;     // MFMA acc

__device__ __forceinline__ int clampi(int v, int lo, int hi) {
  return v < lo ? lo : (v > hi ? hi : v);
}
__device__ __forceinline__ unsigned short f2bf(float f) {  // RNE fp32->bf16
  unsigned int u = __float_as_uint(f);
  return (unsigned short)((u + 0x7FFFu + ((u >> 16) & 1u)) >> 16);
}
__device__ __forceinline__ float bfl(unsigned int u) { return __uint_as_float(u << 16); }
__device__ __forceinline__ float bfh(unsigned int u) { return __uint_as_float(u & 0xFFFF0000u); }
__device__ __forceinline__ float b2f(short s) {
  return __uint_as_float(((unsigned int)(unsigned short)s) << 16);
}

// ---------------- prologue (edges int32 per harness contract) ----------------
// Per-block LDS histograms, 4x uint8 packed per word (slice counts <= ~15 for
// uniform-random edges). dst combos (a=0) also emit each edge's local rank.
__global__ __launch_bounds__(512) void hist6_kernel(
    const int* __restrict__ e, unsigned int* __restrict__ hist,
    unsigned char* __restrict__ rank) {
  __shared__ unsigned int lds[NWW];  // 50 KB -> 2 blocks/CU
  const int b = blockIdx.x;
  const int c = blockIdx.y;
  const int r = c >> 1;
  const int a = c & 1;  // 0: dst (rank emitted), 1: src
  const int tid = threadIdx.x;
  for (int i = tid; i < NWW; i += 512) lds[i] = 0u;
  __syncthreads();
  const size_t abase = (size_t)r * 2 * NE + (a ? 0 : NE);
  const int beg = b * SL, end = min(beg + SL, NE);
  if (a == 0) {
    unsigned char* rk = rank + (size_t)r * NE;
    for (int i = beg + tid; i < end; i += 512) {
      int v = clampi(e[abase + i], 0, NN - 1);
      unsigned int sh = (v & 3) * 8;
      unsigned int old = atomicAdd(&lds[v >> 2], 1u << sh);
      rk[i] = (unsigned char)((old >> sh) & 0xFFu);
    }
  } else {
    for (int i = beg + tid; i < end; i += 512) {
      int v = clampi(e[abase + i], 0, NN - 1);
      atomicAdd(&lds[v >> 2], 1u << ((v & 3) * 8));
    }
  }
  __syncthreads();
  unsigned int* outp = hist + ((size_t)c * NB + b) * NWW;
  for (int i = tid; i < NWW; i += 512) outp[i] = lds[i];
}

// Merged sumhist + local scan. grid (25, 6): block (g,c) covers words
// [g*500, +500) = nodes [g*2000, +2000). a=0: counts -> rsqi + local prefix
// into rowptr + btot. a=1: rsqo only. Packed-field accumulate (16b fields).
__global__ __launch_bounds__(256) void sumscan_kernel(
    const unsigned int* __restrict__ hist, int* __restrict__ rowptr,
    int* __restrict__ btot, float* __restrict__ rsqi, float* __restrict__ rsqo) {
  __shared__ int part[256];
  const int g = blockIdx.x;
  const int c = blockIdx.y;
  const int r = c >> 1, a = c & 1;
  const int t = threadIdx.x;
  int cntv[8];
  int s = 0;
  const int w0 = g * 500 + t * 2;
  if (t < 250) {
#pragma unroll
    for (int j = 0; j < 2; ++j) {
      const unsigned int* hp = hist + (size_t)c * NB * NWW + w0 + j;
      unsigned int accA = 0, accB = 0;  // fields: (b0,b2) and (b1,b3), 16b each
#pragma unroll 12
      for (int b = 0; b < NB; ++b) {
        unsigned int v = hp[(size_t)b * NWW];
        accA += v & 0x00FF00FFu;
        accB += (v >> 8) & 0x00FF00FFu;
      }
      int c0 = (int)(accA & 0xFFFFu), c2 = (int)(accA >> 16);
      int c1 = (int)(accB & 0xFFFFu), c3 = (int)(accB >> 16);
      cntv[4 * j + 0] = c0; cntv[4 * j + 1] = c1;
      cntv[4 * j + 2] = c2; cntv[4 * j + 3] = c3;
      int n0 = 4 * (w0 + j);
      float* rq = (a == 0) ? rsqi : rsqo;
      rq[r * NN + n0 + 0] = rsqrtf(fmaxf((float)c0, 1.0f));
      rq[r * NN + n0 + 1] = rsqrtf(fmaxf((float)c1, 1.0f));
      rq[r * NN + n0 + 2] = rsqrtf(fmaxf((float)c2, 1.0f));
      rq[r * NN + n0 + 3] = rsqrtf(fmaxf((float)c3, 1.0f));
      s += c0 + c1 + c2 + c3;
    }
  }
  if (a == 1) return;  // block-uniform: src combos skip the scan
  part[t] = s;
  __syncthreads();
  for (int off = 1; off < 256; off <<= 1) {
    int x = (t >= off) ? part[t - off] : 0;
    __syncthreads();
    part[t] += x;
    __syncthreads();
  }
  if (t < 250) {
    int excl = part[t] - s;
    int base = g * 2000 + t * 8;
#pragma unroll
    for (int j = 0; j < 8; ++j) {
      rowptr[r * (NN + 1) + base + j] = excl;  // block-LOCAL for now
      excl += cntv[j];
    }
  }
  if (t == 255) btot[r * 25 + g] = part[255];
}

// Tiny: block offsets; writes rowptr[NN] (final).
__global__ __launch_bounds__(64) void scanp2_kernel(
    const int* __restrict__ btot, int* __restrict__ boff, int* __restrict__ rowptr) {
  if (threadIdx.x == 0) {
    for (int r = 0; r < 3; ++r) {
      int run = 0;
      for (int b = 0; b < 25; ++b) {
        boff[r * 25 + b] = run;
        run += btot[r * 25 + b];
      }
      rowptr[r * (NN + 1) + NN] = run;
    }
  }
}

// Finalize rowptr IN PLACE and emit packed uint8 per-histblock deltas
// (prefix of per-block counts; <= deg <= ~50, carry-free packed adds).
__global__ __launch_bounds__(256) void bases_kernel(
    const unsigned int* __restrict__ hist, const int* __restrict__ boff,
    int* __restrict__ rowptr, unsigned int* __restrict__ delta32) {
  const int r = blockIdx.y;
  const int g = blockIdx.x;
  const int off = boff[r * 25 + g];
  for (int wl = threadIdx.x; wl < 500; wl += 256) {
    int wi = g * 500 + wl;
    int n0 = 4 * wi;
#pragma unroll
    for (int k = 0; k < 4; ++k) rowptr[r * (NN + 1) + n0 + k] += off;
    const unsigned int* hp = hist + (size_t)(r * 2) * NB * NWW + wi;
    unsigned int run = 0;  // 4 packed uint8 running prefixes
#pragma unroll 12
    for (int b = 0; b < NB; ++b) {
      delta32[((size_t)r * NB + b) * NWW + wi] = run;
      run += hp[(size_t)b * NWW];  // carry-free: fields stay < 256
    }
  }
}

// Streaming CSR fill: pos = rowptr[d] + delta[histblock][d] + rank. No LDS.
__global__ __launch_bounds__(256) void fillr_kernel(
    const int* __restrict__ e, const unsigned char* __restrict__ rank,
    const unsigned char* __restrict__ delta8, const int* __restrict__ rowptr,
    int* __restrict__ col) {
  const int r = blockIdx.y;
  const int i = blockIdx.x * 256 + threadIdx.x;
  const size_t sbase = (size_t)r * 2 * NE;
  int s = clampi(e[sbase + i], 0, NN - 1);
  int d = clampi(e[sbase + NE + i], 0, NN - 1);
  int b = i / SL;
  int pos = rowptr[r * (NN + 1) + d] +
            (int)delta8[((size_t)r * NB + b) * NN + d] +
            (int)rank[(size_t)r * NE + i];
  pos = clampi(pos, 0, NE - 1);
  col[(size_t)r * NE + pos] = s;
}

// ---------------- weight fragment prep ----------------
// i 0..5: conv_w (128x128); 6: feat_w; 7..9: concat part; 10..11: attn_w[l] (128x64).
__global__ __launch_bounds__(256) void prepw_kernel(
    const float* __restrict__ conv_w, const float* __restrict__ feat_w,
    const float* __restrict__ concat_w, const float* __restrict__ attn_w,
    unsigned short* __restrict__ fw) {
  const int i = blockIdx.x;
  if (i < 10) {
    unsigned short* dst = fw + (size_t)i * 16384;
    for (int e = threadIdx.x; e < 2048; e += 256) {
      int nt = e >> 8, ks = (e >> 6) & 3, lane = e & 63;
      int n = (lane & 15) + nt * 16;
      int kb = (lane >> 4) * 8 + ks * 32;
      unsigned int w[4];
#pragma unroll
      for (int jj = 0; jj < 4; ++jj) {
        int k0 = kb + 2 * jj, k1 = k0 + 1;
        float f0, f1;
        if (i < 6) {
          f0 = conv_w[(size_t)i * 16384 + (size_t)k0 * DD + n];
          f1 = conv_w[(size_t)i * 16384 + (size_t)k1 * DD + n];
        } else if (i == 6) {
          f0 = feat_w[(size_t)k0 * DD + n];
          f1 = feat_w[(size_t)k1 * DD + n];
        } else {
          int p = i - 7;
          f0 = concat_w[(size_t)n * 384 + p * DD + k0];
          f1 = concat_w[(size_t)n * 384 + p * DD + k1];
        }
        w[jj] = (unsigned int)f2bf(f0) | ((unsigned int)f2bf(f1) << 16);
      }
      ((uint4*)dst)[e] = make_uint4(w[0], w[1], w[2], w[3]);
    }
  } else {
    const int l = i - 10;
    unsigned short* dst = fw + (size_t)10 * 16384 + (size_t)l * 8192;
    for (int e = threadIdx.x; e < 1024; e += 256) {
      int nt = e >> 8, ks = (e >> 6) & 3, lane = e & 63;  // nt 0..3
      int n = (lane & 15) + nt * 16;
      int kb = (lane >> 4) * 8 + ks * 32;
      unsigned int w[4];
#pragma unroll
      for (int jj = 0; jj < 4; ++jj) {
        int k0 = kb + 2 * jj, k1 = k0 + 1;
        float f0 = attn_w[((size_t)l * DD + k0) * DQ + n];
        float f1 = attn_w[((size_t)l * DD + k1) * DQ + n];
        w[jj] = (unsigned int)f2bf(f0) | ((unsigned int)f2bf(f1) << 16);
      }
      ((uint4*)dst)[e] = make_uint4(w[0], w[1], w[2], w[3]);
    }
  }
}

// ---------------- MFMA GEMM: Cb = bf16([tanh](A @ W) [*rsqi + bias + residb]) --
template <int AFP32, int TANH, int EPI, int SIX>
__global__ __launch_bounds__(256) void mgemm_kernel(
    const void* __restrict__ Ap, const unsigned short* __restrict__ fw,
    const float* __restrict__ rsqi, const float* __restrict__ bias,
    const unsigned short* __restrict__ residb, unsigned short* __restrict__ Cb) {
  const size_t ND = (size_t)NN * DD;
  const int rel = blockIdx.y;
  const int wsel = SIX ? (rel + 3) % 6 : rel;
  const int arel = SIX ? rel % 3 : rel;
  const unsigned short* fwp = fw + (size_t)wsel * 16384;
  const float* rsqip = EPI ? rsqi + (size_t)arel * NN : nullptr;
  const float* biasp = EPI ? bias + (size_t)wsel * DD : nullptr;
  unsigned short* Cbp = Cb + (size_t)rel * ND;
  __shared__ unsigned short sF[16384];  // 32 KB
  const int tid = threadIdx.x;
  {
    const float4* s = (const float4*)fwp;
    float4* d = (float4*)sF;
#pragma unroll
    for (int i = 0; i < 8; ++i) d[tid + i * 256] = s[tid + i * 256];
  }
  __syncthreads();
  const int w = tid >> 6, l = tid & 63, la = l & 15, gr = l >> 4;
  const int row0 = blockIdx.x * 128 + w * 32;
  if (row0 >= NN) return;  // after barrier: safe
  const bool m1ok = (row0 + 32) <= NN;  // NN % 16 == 0
  short8_t a[2][4];
#pragma unroll
  for (int m = 0; m < 2; ++m) {
    const int r = row0 + m * 16 + la;
    const bool ok = (m == 0) || m1ok;
    if (AFP32) {
      const float* ap = (const float*)Ap + (size_t)r * DD + gr * 8;
#pragma unroll
      for (int ks = 0; ks < 4; ++ks) {
        short8_t v = (short8_t)0;
        if (ok) {
          float4 x0 = *(const float4*)(ap + ks * 32);
          float4 x1 = *(const float4*)(ap + ks * 32 + 4);
          v[0] = (short)f2bf(x0.x); v[1] = (short)f2bf(x0.y);
          v[2] = (short)f2bf(x0.z); v[3] = (short)f2bf(x0.w);
          v[4] = (short)f2bf(x1.x); v[5] = (short)f2bf(x1.y);
          v[6] = (short)f2bf(x1.z); v[7] = (short)f2bf(x1.w);
        }
        a[m][ks] = v;
      }
    } else {
      const unsigned short* ap =
          (const unsigned short*)Ap + (size_t)arel * ND + (size_t)r * DD + gr * 8;
#pragma unroll
      for (int ks = 0; ks < 4; ++ks)
        a[m][ks] = ok ? *(const short8_t*)(ap + ks * 32) : (short8_t)0;
    }
  }
  f32x4 zero = {0.f, 0.f, 0.f, 0.f};
  f32x4 acc[2][8];
#pragma unroll
  for (int m = 0; m < 2; ++m)
#pragma unroll
    for (int nt = 0; nt < 8; ++nt) acc[m][nt] = zero;
#pragma unroll
  for (int nt = 0; nt < 8; ++nt) {
#pragma unroll
    for (int ks = 0; ks < 4; ++ks) {
      short8_t b = *(const short8_t*)(sF + ((nt * 4 + ks) * 64 + l) * 8);
      acc[0][nt] = __builtin_amdgcn_mfma_f32_16x16x32_bf16(a[0][ks], b, acc[0][nt], 0, 0, 0);
      acc[1][nt] = __builtin_amdgcn_mfma_f32_16x16x32_bf16(a[1][ks], b, acc[1][nt], 0, 0, 0);
    }
  }
#pragma unroll
  for (int m = 0; m < 2; ++m) {
    if (m == 1 && !m1ok) break;
#pragma unroll
    for (int rr = 0; rr < 4; ++rr) {
      const int row = row0 + m * 16 + gr * 4 + rr;
      const float sc = EPI ? rsqip[row] : 0.0f;
#pragma unroll
      for (int nt = 0; nt < 8; ++nt) {
        const int c0 = nt * 16 + la;
        float v = acc[m][nt][rr];
        if (TANH) v = tanhf(v);
        if (EPI) {
          float rv = __uint_as_float((unsigned int)residb[(size_t)row * DD + c0] << 16);
          v = fmaf(v, sc, biasp[c0] + rv);
        }
        Cbp[(size_t)row * DD + c0] = f2bf(v);
      }
    }
  }
}

// ---------------- bf16 CSR gather, batched over gridDim.y = relations --------
#define ACC8(A, V, C) \
  A[0] = fmaf(bfl((V).x), (C), A[0]); A[1] = fmaf(bfh((V).x), (C), A[1]); \
  A[2] = fmaf(bfl((V).y), (C), A[2]); A[3] = fmaf(bfh((V).y), (C), A[3]); \
  A[4] = fmaf(bfl((V).z), (C), A[4]); A[5] = fmaf(bfh((V).z), (C), A[5]); \
  A[6] = fmaf(bfl((V).w), (C), A[6]); A[7] = fmaf(bfh((V).w), (C), A[7]);

__global__ __launch_bounds__(256) void gatherb_kernel(
    const unsigned short* __restrict__ hb, const int* __restrict__ rowptr,
    const int* __restrict__ col, const float* __restrict__ rsqo,
    unsigned short* __restrict__ ub) {
  const size_t ND = (size_t)NN * DD;
  const int rel = blockIdx.y;
  rowptr += (size_t)rel * (NN + 1);
  col += (size_t)rel * NE;
  rsqo += (size_t)rel * NN;
  ub += (size_t)rel * ND;
  int gid = blockIdx.x * 256 + threadIdx.x;
  int n = gid >> 4;
  int lane = gid & 15;
  int e0 = clampi(rowptr[n], 0, NE);
  int e1 = clampi(rowptr[n + 1], e0, NE);
  const uint4* h4 = (const uint4*)hb;  // row = 16 x uint4 (256B)
  float a[8] = {0, 0, 0, 0, 0, 0, 0, 0}, b[8] = {0, 0, 0, 0, 0, 0, 0, 0};
  float c[8] = {0, 0, 0, 0, 0, 0, 0, 0}, d[8] = {0, 0, 0, 0, 0, 0, 0, 0};
  int e = e0;
  for (; e + 7 < e1; e += 8) {
    int s0 = clampi(col[e], 0, NN - 1), s1 = clampi(col[e + 1], 0, NN - 1);
    int s2 = clampi(col[e + 2], 0, NN - 1), s3 = clampi(col[e + 3], 0, NN - 1);
    int s4 = clampi(col[e + 4], 0, NN - 1), s5 = clampi(col[e + 5], 0, NN - 1);
    int s6 = clampi(col[e + 6], 0, NN - 1), s7 = clampi(col[e + 7], 0, NN - 1);
    float c0 = rsqo[s0], c1 = rsqo[s1], c2 = rsqo[s2], c3 = rsqo[s3];
    float c4 = rsqo[s4], c5 = rsqo[s5], c6 = rsqo[s6], c7 = rsqo[s7];
    uint4 v0 = h4[(size_t)s0 * 16 + lane];
    uint4 v1 = h4[(size_t)s1 * 16 + lane];
    uint4 v2 = h4[(size_t)s2 * 16 + lane];
    uint4 v3 = h4[(size_t)s3 * 16 + lane];
    uint4 v4 = h4[(size_t)s4 * 16 + lane];
    uint4 v5 = h4[(size_t)s5 * 16 + lane];
    uint4 v6 = h4[(size_t)s6 * 16 + lane];
    uint4 v7 = h4[(size_t)s7 * 16 + lane];
    ACC8(a, v0, c0) ACC8(b, v1, c1) ACC8(c, v2, c2) ACC8(d, v3, c3)
    ACC8(a, v4, c4) ACC8(b, v5, c5) ACC8(c, v6, c6) ACC8(d, v7, c7)
  }
  for (; e + 3 < e1; e += 4) {
    int s0 = clampi(col[e], 0, NN - 1), s1 = clampi(col[e + 1], 0, NN - 1);
    int s2 = clampi(col[e + 2], 0, NN - 1), s3 = clampi(col[e + 3], 0, NN - 1);
    float c0 = rsqo[s0], c1 = rsqo[s1], c2 = rsqo[s2], c3 = rsqo[s3];
    uint4 v0 = h4[(size_t)s0 * 16 + lane];
    uint4 v1 = h4[(size_t)s1 * 16 + lane];
    uint4 v2 = h4[(size_t)s2 * 16 + lane];
    uint4 v3 = h4[(size_t)s3 * 16 + lane];
    ACC8(a, v0, c0) ACC8(b, v1, c1) ACC8(c, v2, c2) ACC8(d, v3, c3)
  }
  for (; e < e1; ++e) {
    int s0 = clampi(col[e], 0, NN - 1);
    float c0 = rsqo[s0];
    uint4 v0 = h4[(size_t)s0 * 16 + lane];
    ACC8(a, v0, c0)
  }
#pragma unroll
  for (int j = 0; j < 8; ++j) a[j] += b[j] + c[j] + d[j];
  uint4 o;
  o.x = (unsigned int)f2bf(a[0]) | ((unsigned int)f2bf(a[1]) << 16);
  o.y = (unsigned int)f2bf(a[2]) | ((unsigned int)f2bf(a[3]) << 16);
  o.z = (unsigned int)f2bf(a[4]) | ((unsigned int)f2bf(a[5]) << 16);
  o.w = (unsigned int)f2bf(a[6]) | ((unsigned int)f2bf(a[7]) << 16);
  ((uint4*)ub)[gid] = o;
}

// ------- fused MFMA scores + softmax + combine (dual-layer, h1/t producer) ---
__global__ __launch_bounds__(256) void mscomb_kernel(
    const unsigned short* __restrict__ Vb, const unsigned short* __restrict__ faB,
    const float* __restrict__ AQB, unsigned short* __restrict__ houtB) {
  const size_t ND = (size_t)NN * DD;
  const int y = blockIdx.y;
  const unsigned short* Vp = Vb + (size_t)y * 3 * ND;
  const unsigned short* fa = faB + (size_t)(1 - y) * 8192;
  const float* AQ = AQB + (size_t)(1 - y) * DQ;
  unsigned short* houtb = houtB + (size_t)y * ND;
  __shared__ unsigned short sF[8192];  // 16 KB
  __shared__ float sS[4][3][32];
  const int tid = threadIdx.x;
  {
    const float4* s = (const float4*)fa;
    float4* d = (float4*)sF;
#pragma unroll
    for (int i = 0; i < 4; ++i) d[tid + i * 256] = s[tid + i * 256];
  }
  const int w = tid >> 6, l = tid & 63, la = l & 15, gr = l >> 4;
  int row0 = blockIdx.x * 128 + w * 32;
  if (row0 + 32 > NN) row0 = NN - 32;  // clamp (dup rows idempotent)
  short8_t a[3][2][4];
#pragma unroll
  for (int r3 = 0; r3 < 3; ++r3) {
#pragma unroll
    for (int m = 0; m < 2; ++m) {
      const unsigned short* rp =
          Vp + (size_t)r3 * ND + (size_t)(row0 + m * 16 + la) * DD + gr * 8;
#pragma unroll
      for (int ks = 0; ks < 4; ++ks)
        a[r3][m][ks] = *(const short8_t*)(rp + ks * 32);
    }
  }
  __syncthreads();  // sF ready
  float q[4];
#pragma unroll
  for (int nt = 0; nt < 4; ++nt) q[nt] = AQ[la + nt * 16];
#pragma unroll
  for (int r3 = 0; r3 < 3; ++r3) {
    f32x4 zero = {0.f, 0.f, 0.f, 0.f};
    f32x4 acc[2][4];
#pragma unroll
    for (int m = 0; m < 2; ++m)
#pragma unroll
      for (int nt = 0; nt < 4; ++nt) acc[m][nt] = zero;
#pragma unroll
    for (int nt = 0; nt < 4; ++nt) {
#pragma unroll
      for (int ks = 0; ks < 4; ++ks) {
        short8_t b = *(const short8_t*)(sF + ((nt * 4 + ks) * 64 + l) * 8);
        acc[0][nt] = __builtin_amdgcn_mfma_f32_16x16x32_bf16(a[r3][0][ks], b, acc[0][nt], 0, 0, 0);
        acc[1][nt] = __builtin_amdgcn_mfma_f32_16x16x32_bf16(a[r3][1][ks], b, acc[1][nt], 0, 0, 0);
      }
    }
#pragma unroll
    for (int m = 0; m < 2; ++m) {
#pragma unroll
      for (int rr = 0; rr < 4; ++rr) {
        float p = tanhf(acc[m][0][rr]) * q[0] + tanhf(acc[m][1][rr]) * q[1] +
                  tanhf(acc[m][2][rr]) * q[2] + tanhf(acc[m][3][rr]) * q[3];
#pragma unroll
        for (int off = 1; off < 16; off <<= 1) p += __shfl_xor(p, off, 16);
        if (la == 0) sS[w][r3][m * 16 + gr * 4 + rr] = p;
      }
    }
  }
  __syncthreads();
#pragma unroll
  for (int m = 0; m < 2; ++m) {
    const int row = row0 + m * 16 + la;
    float s0 = sS[w][0][m * 16 + la];
    float s1 = sS[w][1][m * 16 + la];
    float s2 = sS[w][2][m * 16 + la];
    float mx = fmaxf(s0, fmaxf(s1, s2));
    float e0 = __expf(s0 - mx), e1 = __expf(s1 - mx), e2 = __expf(s2 - mx);
    float inv = 1.0f / (e0 + e1 + e2);
    float a0 = e0 * inv, a1 = e1 * inv, a2 = e2 * inv;
#pragma unroll
    for (int ks = 0; ks < 4; ++ks) {
      unsigned int ow[4];
#pragma unroll
      for (int jj = 0; jj < 4; ++jj) {
        float v0 = a0 * b2f(a[0][m][ks][2 * jj]) + a1 * b2f(a[1][m][ks][2 * jj]) +
                   a2 * b2f(a[2][m][ks][2 * jj]);
        float v1 = a0 * b2f(a[0][m][ks][2 * jj + 1]) + a1 * b2f(a[1][m][ks][2 * jj + 1]) +
                   a2 * b2f(a[2][m][ks][2 * jj + 1]);
        ow[jj] = (unsigned int)f2bf(v0) | ((unsigned int)f2bf(v1) << 16);
      }
      *(uint4*)(houtb + (size_t)row * DD + gr * 8 + ks * 32) =
          make_uint4(ow[0], ow[1], ow[2], ow[3]);
    }
  }
}

// ------- final layer: scores + softmax + combine + FUSED CONCAT --------------
// h2 never hits memory: after combine it sits in A-frag layout registers and
// feeds the p=2 concat pass directly. y = h0@B7 + h1@B8 + h2@B9 -> out (fp32).
__global__ __launch_bounds__(256) void mscombc_kernel(
    const unsigned short* __restrict__ Vb, const unsigned short* __restrict__ fa,
    const float* __restrict__ AQ, const unsigned short* __restrict__ h0b,
    const unsigned short* __restrict__ h1b, const unsigned short* __restrict__ fwc,
    float* __restrict__ Y, float* __restrict__ attn_out) {
  const size_t ND = (size_t)NN * DD;
  __shared__ unsigned short sF[8192];   // 16 KB attn frags
  __shared__ unsigned short sC[16384];  // 32 KB concat frags (reloaded per p)
  __shared__ float sS[4][3][32];
  const int tid = threadIdx.x;
  {
    const float4* s = (const float4*)fa;
    float4* d = (float4*)sF;
#pragma unroll
    for (int i = 0; i < 4; ++i) d[tid + i * 256] = s[tid + i * 256];
  }
  const int w = tid >> 6, l = tid & 63, la = l & 15, gr = l >> 4;
  int row0 = blockIdx.x * 128 + w * 32;
  if (row0 + 32 > NN) row0 = NN - 32;  // clamp (dup rows idempotent)
  short8_t a[3][2][4];
#pragma unroll
  for (int r3 = 0; r3 < 3; ++r3) {
#pragma unroll
    for (int m = 0; m < 2; ++m) {
      const unsigned short* rp =
          Vb + (size_t)r3 * ND + (size_t)(row0 + m * 16 + la) * DD + gr * 8;
#pragma unroll
      for (int ks = 0; ks < 4; ++ks)
        a[r3][m][ks] = *(const short8_t*)(rp + ks * 32);
    }
  }
  __syncthreads();  // sF ready
  float q[4];
#pragma unroll
  for (int nt = 0; nt < 4; ++nt) q[nt] = AQ[la + nt * 16];
#pragma unroll
  for (int r3 = 0; r3 < 3; ++r3) {
    f32x4 zero = {0.f, 0.f, 0.f, 0.f};
    f32x4 acc[2][4];
#pragma unroll
    for (int m = 0; m < 2; ++m)
#pragma unroll
      for (int nt = 0; nt < 4; ++nt) acc[m][nt] = zero;
#pragma unroll
    for (int nt = 0; nt < 4; ++nt) {
#pragma unroll
      for (int ks = 0; ks < 4; ++ks) {
        short8_t b = *(const short8_t*)(sF + ((nt * 4 + ks) * 64 + l) * 8);
        acc[0][nt] = __builtin_amdgcn_mfma_f32_16x16x32_bf16(a[r3][0][ks], b, acc[0][nt], 0, 0, 0);
        acc[1][nt] = __builtin_amdgcn_mfma_f32_16x16x32_bf16(a[r3][1][ks], b, acc[1][nt], 0, 0, 0);
      }
    }
#pragma unroll
    for (int m = 0; m < 2; ++m) {
#pragma unroll
      for (int rr = 0; rr < 4; ++rr) {
        float p = tanhf(acc[m][0][rr]) * q[0] + tanhf(acc[m][1][rr]) * q[1] +
                  tanhf(acc[m][2][rr]) * q[2] + tanhf(acc[m][3][rr]) * q[3];
#pragma unroll
        for (int off = 1; off < 16; off <<= 1) p += __shfl_xor(p, off, 16);
        if (la == 0) sS[w][r3][m * 16 + gr * 4 + rr] = p;
      }
    }
  }
  __syncthreads();
  // softmax + combine IN PLACE into a[0] (per (m,ks): reads a[*][m][ks] only)
#pragma unroll
  for (int m = 0; m < 2; ++m) {
    const int row = row0 + m * 16 + la;
    float s0 = sS[w][0][m * 16 + la];
    float s1 = sS[w][1][m * 16 + la];
    float s2 = sS[w][2][m * 16 + la];
    float mx = fmaxf(s0, fmaxf(s1, s2));
    float e0 = __expf(s0 - mx), e1 = __expf(s1 - mx), e2 = __expf(s2 - mx);
    float inv = 1.0f / (e0 + e1 + e2);
    float a0 = e0 * inv, a1 = e1 * inv, a2 = e2 * inv;
#pragma unroll
    for (int ks = 0; ks < 4; ++ks) {
#pragma unroll
      for (int jj = 0; jj < 8; ++jj) {
        float v = a0 * b2f(a[0][m][ks][jj]) + a1 * b2f(a[1][m][ks][jj]) +
                  a2 * b2f(a[2][m][ks][jj]);
        a[0][m][ks][jj] = (short)f2bf(v);
      }
    }
    attn_out[(size_t)row * 3 + 0] = a0;
    attn_out[(size_t)row * 3 + 1] = a1;
    attn_out[(size_t)row * 3 + 2] = a2;
  }
  // concat: y = h0@B0f + h1@B1f + h2@B2f
  f32x4 zero = {0.f, 0.f, 0.f, 0.f};
  f32x4 yacc[2][8];
#pragma unroll
  for (int m = 0; m < 2; ++m)
#pragma unroll
    for (int nt = 0; nt < 8; ++nt) yacc[m][nt] = zero;
#pragma unroll
  for (int p = 0; p < 3; ++p) {
    __syncthreads();  // previous sC use complete
    {
      const float4* s = (const float4*)(fwc + (size_t)p * 16384);
      float4* d = (float4*)sC;
#pragma unroll
      for (int i = 0; i < 8; ++i) d[tid + i * 256] = s[tid + i * 256];
    }
    __syncthreads();
    short8_t af[2][4];
    if (p == 2) {
#pragma unroll
      for (int m = 0; m < 2; ++m)
#pragma unroll
        for (int ks = 0; ks < 4; ++ks) af[m][ks] = a[0][m][ks];
    } else {
      const unsigned short* hp = (p == 0) ? h0b : h1b;
#pragma unroll
      for (int m = 0; m < 2; ++m) {
        const unsigned short* rp = hp + (size_t)(row0 + m * 16 + la) * DD + gr * 8;
#pragma unroll
        for (int ks = 0; ks < 4; ++ks) af[m][ks] = *(const short8_t*)(rp + ks * 32);
      }
    }
#pragma unroll
    for (int nt = 0; nt < 8; ++nt) {
#pragma unroll
      for (int ks = 0; ks < 4; ++ks) {
        short8_t b = *(const short8_t*)(sC + ((nt * 4 + ks) * 64 + l) * 8);
        yacc[0][nt] = __builtin_amdgcn_mfma_f32_16x16x32_bf16(af[0][ks], b, yacc[0][nt], 0, 0, 0);
        yacc[1][nt] = __builtin_amdgcn_mfma_f32_16x16x32_bf16(af[1][ks], b, yacc[1][nt], 0, 0, 0);
      }
    }
  }
#pragma unroll
  for (int m = 0; m < 2; ++m) {
#pragma unroll
    for (int rr = 0; rr < 4; ++rr) {
      const int row = row0 + m * 16 + gr * 4 + rr;
#pragma unroll
      for (int nt = 0; nt < 8; ++nt)
        Y[(size_t)row * DD + nt * 16 + la] = yacc[m][nt][rr];
    }
  }
}

extern "C" void kernel_launch(void* const* d_in, const int* in_sizes, int n_in,
                              void* d_out, int out_size, void* d_ws, size_t ws_size,
                              hipStream_t stream) {
  const float* x        = (const float*)d_in[0];
  const int*   edges    = (const int*)d_in[1];
  const float* feat_w   = (const float*)d_in[2];
  const float* conv_w   = (const float*)d_in[3];
  const float* conv_b   = (const float*)d_in[4];
  const float* attn_w   = (const float*)d_in[5];
  const float* attn_q   = (const float*)d_in[6];
  const float* concat_w = (const float*)d_in[7];
  float* out = (float*)d_out;   // [NN*128 y][NN*3 attn]

  float* ws = (float*)d_ws;
  float* rsqo = ws;                   // [3][NN]
  float* rsqi = rsqo + 3 * NN;        // [3][NN]
  int* btot = (int*)(rsqi + 3 * NN);  // 80 ints
  int* boff = btot + 80;              // 80 ints
  int* cnt = boff + 96;               // spare region; fw overlays here
  int* rowptr = cnt + 3 * NN;         // [3][NN+1] (+pad)
  int* col = rowptr + 3 * (NN + 1) + 13;  // [3][NE]
  const size_t ND = (size_t)NN * DD;
  float* P1 = (float*)(col + 3 * (size_t)NE);  // prologue: rank8 | VbAll 0-1
  float* PA = P1 + ND;   // prologue: hist | VbAll planes 2-3
  float* PB = PA + ND;   // prologue: delta8 | VbAll planes 4-5
  unsigned short* U0 = (unsigned short*)(PB + ND);  // u bf16 x3
  unsigned short* B0 = U0 + 3 * ND;   // h0b
  unsigned short* B1 = B0 + ND;       // h1b
  unsigned short* B2 = B1 + ND;       // tb
  unsigned short* fw = (unsigned short*)cnt;   // 10x16384 + 2x8192 ushort
  unsigned int* hist = (unsigned int*)PA;      // [6][NB][NWW] = 25.2 MB <= plane
  unsigned char* delta8 = (unsigned char*)PB;  // [3][NB][NN] = 12.6 MB <= plane
  unsigned char* rank8 = (unsigned char*)P1;   // [3][NE] = 2.4 MB <= plane
  unsigned short* VbAll = (unsigned short*)P1; // 6 bf16 vals planes (contig)
  unsigned short* fa0 = fw + (size_t)10 * 16384;
  unsigned short* fa1 = fa0 + 8192;

  // prologue: degrees + CSR (no global atomics, byte-packed, 2 blocks/CU)
  hist6_kernel<<<dim3(NB, 6), 512, 0, stream>>>(edges, hist, rank8);
  sumscan_kernel<<<dim3(25, 6), 256, 0, stream>>>(hist, rowptr, btot, rsqi, rsqo);
  scanp2_kernel<<<1, 64, 0, stream>>>(btot, boff, rowptr);
  prepw_kernel<<<12, 256, 0, stream>>>(conv_w, feat_w, concat_w, attn_w, fw);
  bases_kernel<<<dim3(25, 3), 256, 0, stream>>>(hist, boff, rowptr, (unsigned int*)delta8);
  fillr_kernel<<<dim3(3125, 3), 256, 0, stream>>>(edges, rank8, delta8, rowptr, col);

  // h0 = tanh(x @ feat_w) -> B0 bf16
  mgemm_kernel<1, 1, 0, 0><<<dim3(391, 1), 256, 0, stream>>>(
      x, fw + (size_t)6 * 16384, nullptr, nullptr, nullptr, B0);

  // shared u[r] = A_r^T (h0 * rsqo_r) -> U planes, batched
  gatherb_kernel<<<dim3(3125, 3), 256, 0, stream>>>(B0, rowptr, col, rsqo, U0);

  // both h0-fed layers in one launch: planes 0-2 = l1 vals, 3-5 = l0 vals
  mgemm_kernel<0, 0, 1, 1><<<dim3(391, 6), 256, 0, stream>>>(
      U0, fw, rsqi, conv_b, B0, VbAll);
  // both mscombs in one launch: h1 -> B1, t -> B2
  mscomb_kernel<<<dim3(391, 2), 256, 0, stream>>>(VbAll, fa0, attn_q, B1);

  // layer l=1 on t: gathers from B2 -> U; convs (resid = B2) -> planes 0-2
  gatherb_kernel<<<dim3(3125, 3), 256, 0, stream>>>(B2, rowptr, col, rsqo, U0);
  mgemm_kernel<0, 0, 1, 0><<<dim3(391, 3), 256, 0, stream>>>(
      U0, fw + (size_t)3 * 16384, rsqi, conv_b + (size_t)3 * DD, B2, VbAll);
  // final: scores+softmax+combine+concat fused; h2 stays in registers.
  // y -> out, attn -> out+ND
  mscombc_kernel<<<391, 256, 0, stream>>>(
      VbAll, fa1, attn_q + DQ, B0, B1, fw + (size_t)7 * 16384, out, out + ND);
}

// Round 13
// 427.127 us; speedup vs baseline: 1.0857x; 1.0857x over previous
//
#include <hip/hip_runtime.h>

#define NN 50000
#define NE 800000
#define DD 128
#define DQ 64
#define NB 42          // histogram/fill blocks per (relation, array)
#define SL 19048       // edge slice per block: 42*19048 >= NE
#define NWW 12500      // packed uint8x4 words covering NN counters

typedef __attribute__((ext_vector_type(8))) short short8_t;  // 8 bf16 (4 VGPR)
typedef __attribute__((ext_vector_type(4))) float f32x4;     // MFMA acc

__device__ __forceinline__ int clampi(int v, int lo, int hi) {
  return v < lo ? lo : (v > hi ? hi : v);
}
__device__ __forceinline__ unsigned short f2bf(float f) {  // RNE fp32->bf16
  unsigned int u = __float_as_uint(f);
  return (unsigned short)((u + 0x7FFFu + ((u >> 16) & 1u)) >> 16);
}
__device__ __forceinline__ float bfl(unsigned int u) { return __uint_as_float(u << 16); }
__device__ __forceinline__ float bfh(unsigned int u) { return __uint_as_float(u & 0xFFFF0000u); }
__device__ __forceinline__ float b2f(short s) {
  return __uint_as_float(((unsigned int)(unsigned short)s) << 16);
}

// ---------------- prologue (edges int32 per harness contract) ----------------
// Per-block LDS histograms, 4x uint8 packed per word (slice counts <= ~12 for
// uniform-random edges; NB=42 keeps downstream loops at 42-deep).
// dst combos (a=0) also emit each edge's local rank (uint8).
__global__ __launch_bounds__(512) void hist6_kernel(
    const int* __restrict__ e, unsigned int* __restrict__ hist,
    unsigned char* __restrict__ rank) {
  __shared__ unsigned int lds[NWW];  // 50 KB -> 2 blocks/CU
  const int b = blockIdx.x;
  const int c = blockIdx.y;
  const int r = c >> 1;
  const int a = c & 1;  // 0: dst (rank emitted), 1: src
  const int tid = threadIdx.x;
  for (int i = tid; i < NWW; i += 512) lds[i] = 0u;
  __syncthreads();
  const size_t abase = (size_t)r * 2 * NE + (a ? 0 : NE);
  const int beg = b * SL, end = min(beg + SL, NE);
  if (a == 0) {
    unsigned char* rk = rank + (size_t)r * NE;
    for (int i = beg + tid; i < end; i += 512) {
      int v = clampi(e[abase + i], 0, NN - 1);
      unsigned int sh = (v & 3) * 8;
      unsigned int old = atomicAdd(&lds[v >> 2], 1u << sh);
      rk[i] = (unsigned char)((old >> sh) & 0xFFu);
    }
  } else {
    for (int i = beg + tid; i < end; i += 512) {
      int v = clampi(e[abase + i], 0, NN - 1);
      atomicAdd(&lds[v >> 2], 1u << ((v & 3) * 8));
    }
  }
  __syncthreads();
  unsigned int* outp = hist + ((size_t)c * NB + b) * NWW;
  for (int i = tid; i < NWW; i += 512) outp[i] = lds[i];
}

// Merged sumhist + local scan. grid (25, 6): block (g,c) covers words
// [g*500, +500) = nodes [g*2000, +2000). a=0: counts -> rsqi + local prefix
// into rowptr (block-LOCAL) + btot. a=1: rsqo only.
__global__ __launch_bounds__(256) void sumscan_kernel(
    const unsigned int* __restrict__ hist, int* __restrict__ rowptr,
    int* __restrict__ btot, float* __restrict__ rsqi, float* __restrict__ rsqo) {
  __shared__ int part[256];
  const int g = blockIdx.x;
  const int c = blockIdx.y;
  const int r = c >> 1, a = c & 1;
  const int t = threadIdx.x;
  int cntv[8];
  int s = 0;
  const int w0 = g * 500 + t * 2;
  if (t < 250) {
#pragma unroll
    for (int j = 0; j < 2; ++j) {
      const unsigned int* hp = hist + (size_t)c * NB * NWW + w0 + j;
      unsigned int accA = 0, accB = 0;  // fields: (b0,b2) and (b1,b3), 16b each
#pragma unroll 6
      for (int b = 0; b < NB; ++b) {
        unsigned int v = hp[(size_t)b * NWW];
        accA += v & 0x00FF00FFu;
        accB += (v >> 8) & 0x00FF00FFu;
      }
      int c0 = (int)(accA & 0xFFFFu), c2 = (int)(accA >> 16);
      int c1 = (int)(accB & 0xFFFFu), c3 = (int)(accB >> 16);
      cntv[4 * j + 0] = c0; cntv[4 * j + 1] = c1;
      cntv[4 * j + 2] = c2; cntv[4 * j + 3] = c3;
      int n0 = 4 * (w0 + j);
      float* rq = (a == 0) ? rsqi : rsqo;
      rq[r * NN + n0 + 0] = rsqrtf(fmaxf((float)c0, 1.0f));
      rq[r * NN + n0 + 1] = rsqrtf(fmaxf((float)c1, 1.0f));
      rq[r * NN + n0 + 2] = rsqrtf(fmaxf((float)c2, 1.0f));
      rq[r * NN + n0 + 3] = rsqrtf(fmaxf((float)c3, 1.0f));
      s += c0 + c1 + c2 + c3;
    }
  }
  if (a == 1) return;  // block-uniform: src combos skip the scan
  part[t] = s;
  __syncthreads();
  for (int off = 1; off < 256; off <<= 1) {
    int x = (t >= off) ? part[t - off] : 0;
    __syncthreads();
    part[t] += x;
    __syncthreads();
  }
  if (t < 250) {
    int excl = part[t] - s;
    int base = g * 2000 + t * 8;
#pragma unroll
    for (int j = 0; j < 8; ++j) {
      rowptr[r * (NN + 1) + base + j] = excl;  // block-LOCAL for now
      excl += cntv[j];
    }
  }
  if (t == 255) btot[r * 25 + g] = part[255];
}

// Tiny: block offsets; writes rowptr[NN] (final).
__global__ __launch_bounds__(64) void scanp2_kernel(
    const int* __restrict__ btot, int* __restrict__ boff, int* __restrict__ rowptr) {
  if (threadIdx.x == 0) {
    for (int r = 0; r < 3; ++r) {
      int run = 0;
      for (int b = 0; b < 25; ++b) {
        boff[r * 25 + b] = run;
        run += btot[r * 25 + b];
      }
      rowptr[r * (NN + 1) + NN] = run;
    }
  }
}

// Finalize rowptr IN PLACE and emit packed uint8 per-histblock deltas
// (prefix of per-block counts; <= deg <= ~50, carry-free packed adds).
__global__ __launch_bounds__(256) void bases_kernel(
    const unsigned int* __restrict__ hist, const int* __restrict__ boff,
    int* __restrict__ rowptr, unsigned int* __restrict__ delta32) {
  const int r = blockIdx.y;
  const int g = blockIdx.x;
  const int off = boff[r * 25 + g];
  for (int wl = threadIdx.x; wl < 500; wl += 256) {
    int wi = g * 500 + wl;
    int n0 = 4 * wi;
#pragma unroll
    for (int k = 0; k < 4; ++k) rowptr[r * (NN + 1) + n0 + k] += off;
    const unsigned int* hp = hist + (size_t)(r * 2) * NB * NWW + wi;
    unsigned int run = 0;  // 4 packed uint8 running prefixes
#pragma unroll 6
    for (int b = 0; b < NB; ++b) {
      delta32[((size_t)r * NB + b) * NWW + wi] = run;
      run += hp[(size_t)b * NWW];  // carry-free: fields stay < 256
    }
  }
}

// Streaming CSR fill: pos = rowptr[d] + delta[histblock][d] + rank. No LDS.
__global__ __launch_bounds__(256) void fillr_kernel(
    const int* __restrict__ e, const unsigned char* __restrict__ rank,
    const unsigned char* __restrict__ delta8, const int* __restrict__ rowptr,
    int* __restrict__ col) {
  const int r = blockIdx.y;
  const int i = blockIdx.x * 256 + threadIdx.x;
  const size_t sbase = (size_t)r * 2 * NE;
  int s = clampi(e[sbase + i], 0, NN - 1);
  int d = clampi(e[sbase + NE + i], 0, NN - 1);
  int b = i / SL;
  int pos = rowptr[r * (NN + 1) + d] +
            (int)delta8[((size_t)r * NB + b) * NN + d] +
            (int)rank[(size_t)r * NE + i];
  pos = clampi(pos, 0, NE - 1);
  col[(size_t)r * NE + pos] = s;
}

// ---------------- weight fragment prep ----------------
// i 0..5: conv_w (128x128); 6: feat_w; 7..9: concat part; 10..11: attn_w[l] (128x64).
__global__ __launch_bounds__(256) void prepw_kernel(
    const float* __restrict__ conv_w, const float* __restrict__ feat_w,
    const float* __restrict__ concat_w, const float* __restrict__ attn_w,
    unsigned short* __restrict__ fw) {
  const int i = blockIdx.x;
  if (i < 10) {
    unsigned short* dst = fw + (size_t)i * 16384;
    for (int e = threadIdx.x; e < 2048; e += 256) {
      int nt = e >> 8, ks = (e >> 6) & 3, lane = e & 63;
      int n = (lane & 15) + nt * 16;
      int kb = (lane >> 4) * 8 + ks * 32;
      unsigned int w[4];
#pragma unroll
      for (int jj = 0; jj < 4; ++jj) {
        int k0 = kb + 2 * jj, k1 = k0 + 1;
        float f0, f1;
        if (i < 6) {
          f0 = conv_w[(size_t)i * 16384 + (size_t)k0 * DD + n];
          f1 = conv_w[(size_t)i * 16384 + (size_t)k1 * DD + n];
        } else if (i == 6) {
          f0 = feat_w[(size_t)k0 * DD + n];
          f1 = feat_w[(size_t)k1 * DD + n];
        } else {
          int p = i - 7;
          f0 = concat_w[(size_t)n * 384 + p * DD + k0];
          f1 = concat_w[(size_t)n * 384 + p * DD + k1];
        }
        w[jj] = (unsigned int)f2bf(f0) | ((unsigned int)f2bf(f1) << 16);
      }
      ((uint4*)dst)[e] = make_uint4(w[0], w[1], w[2], w[3]);
    }
  } else {
    const int l = i - 10;
    unsigned short* dst = fw + (size_t)10 * 16384 + (size_t)l * 8192;
    for (int e = threadIdx.x; e < 1024; e += 256) {
      int nt = e >> 8, ks = (e >> 6) & 3, lane = e & 63;  // nt 0..3
      int n = (lane & 15) + nt * 16;
      int kb = (lane >> 4) * 8 + ks * 32;
      unsigned int w[4];
#pragma unroll
      for (int jj = 0; jj < 4; ++jj) {
        int k0 = kb + 2 * jj, k1 = k0 + 1;
        float f0 = attn_w[((size_t)l * DD + k0) * DQ + n];
        float f1 = attn_w[((size_t)l * DD + k1) * DQ + n];
        w[jj] = (unsigned int)f2bf(f0) | ((unsigned int)f2bf(f1) << 16);
      }
      ((uint4*)dst)[e] = make_uint4(w[0], w[1], w[2], w[3]);
    }
  }
}

// ---------------- MFMA GEMM: Cb = bf16([tanh](A @ W) [*rsqi + bias + residb]) --
template <int AFP32, int TANH, int EPI, int SIX>
__global__ __launch_bounds__(256) void mgemm_kernel(
    const void* __restrict__ Ap, const unsigned short* __restrict__ fw,
    const float* __restrict__ rsqi, const float* __restrict__ bias,
    const unsigned short* __restrict__ residb, unsigned short* __restrict__ Cb) {
  const size_t ND = (size_t)NN * DD;
  const int rel = blockIdx.y;
  const int wsel = SIX ? (rel + 3) % 6 : rel;
  const int arel = SIX ? rel % 3 : rel;
  const unsigned short* fwp = fw + (size_t)wsel * 16384;
  const float* rsqip = EPI ? rsqi + (size_t)arel * NN : nullptr;
  const float* biasp = EPI ? bias + (size_t)wsel * DD : nullptr;
  unsigned short* Cbp = Cb + (size_t)rel * ND;
  __shared__ unsigned short sF[16384];  // 32 KB
  const int tid = threadIdx.x;
  {
    const float4* s = (const float4*)fwp;
    float4* d = (float4*)sF;
#pragma unroll
    for (int i = 0; i < 8; ++i) d[tid + i * 256] = s[tid + i * 256];
  }
  __syncthreads();
  const int w = tid >> 6, l = tid & 63, la = l & 15, gr = l >> 4;
  const int row0 = blockIdx.x * 128 + w * 32;
  if (row0 >= NN) return;  // after barrier: safe
  const bool m1ok = (row0 + 32) <= NN;  // NN % 16 == 0
  short8_t a[2][4];
#pragma unroll
  for (int m = 0; m < 2; ++m) {
    const int r = row0 + m * 16 + la;
    const bool ok = (m == 0) || m1ok;
    if (AFP32) {
      const float* ap = (const float*)Ap + (size_t)r * DD + gr * 8;
#pragma unroll
      for (int ks = 0; ks < 4; ++ks) {
        short8_t v = (short8_t)0;
        if (ok) {
          float4 x0 = *(const float4*)(ap + ks * 32);
          float4 x1 = *(const float4*)(ap + ks * 32 + 4);
          v[0] = (short)f2bf(x0.x); v[1] = (short)f2bf(x0.y);
          v[2] = (short)f2bf(x0.z); v[3] = (short)f2bf(x0.w);
          v[4] = (short)f2bf(x1.x); v[5] = (short)f2bf(x1.y);
          v[6] = (short)f2bf(x1.z); v[7] = (short)f2bf(x1.w);
        }
        a[m][ks] = v;
      }
    } else {
      const unsigned short* ap =
          (const unsigned short*)Ap + (size_t)arel * ND + (size_t)r * DD + gr * 8;
#pragma unroll
      for (int ks = 0; ks < 4; ++ks)
        a[m][ks] = ok ? *(const short8_t*)(ap + ks * 32) : (short8_t)0;
    }
  }
  f32x4 zero = {0.f, 0.f, 0.f, 0.f};
  f32x4 acc[2][8];
#pragma unroll
  for (int m = 0; m < 2; ++m)
#pragma unroll
    for (int nt = 0; nt < 8; ++nt) acc[m][nt] = zero;
#pragma unroll
  for (int nt = 0; nt < 8; ++nt) {
#pragma unroll
    for (int ks = 0; ks < 4; ++ks) {
      short8_t b = *(const short8_t*)(sF + ((nt * 4 + ks) * 64 + l) * 8);
      acc[0][nt] = __builtin_amdgcn_mfma_f32_16x16x32_bf16(a[0][ks], b, acc[0][nt], 0, 0, 0);
      acc[1][nt] = __builtin_amdgcn_mfma_f32_16x16x32_bf16(a[1][ks], b, acc[1][nt], 0, 0, 0);
    }
  }
#pragma unroll
  for (int m = 0; m < 2; ++m) {
    if (m == 1 && !m1ok) break;
#pragma unroll
    for (int rr = 0; rr < 4; ++rr) {
      const int row = row0 + m * 16 + gr * 4 + rr;
      const float sc = EPI ? rsqip[row] : 0.0f;
#pragma unroll
      for (int nt = 0; nt < 8; ++nt) {
        const int c0 = nt * 16 + la;
        float v = acc[m][nt][rr];
        if (TANH) v = tanhf(v);
        if (EPI) {
          float rv = __uint_as_float((unsigned int)residb[(size_t)row * DD + c0] << 16);
          v = fmaf(v, sc, biasp[c0] + rv);
        }
        Cbp[(size_t)row * DD + c0] = f2bf(v);
      }
    }
  }
}

// ---------------- MFMA concat: y = sum_p hb[p] @ Bp (K=384) ----------------
__global__ __launch_bounds__(512) void mconcat_kernel(
    const unsigned short* __restrict__ h0b, const unsigned short* __restrict__ h1b,
    const unsigned short* __restrict__ h2b, const unsigned short* __restrict__ fwc,
    float* __restrict__ Y) {
  __shared__ unsigned short sF[3 * 16384];  // 96 KB
  const int tid = threadIdx.x;
  {
    const float4* s = (const float4*)fwc;
    float4* d = (float4*)sF;
#pragma unroll
    for (int i = 0; i < 12; ++i) d[tid + i * 512] = s[tid + i * 512];
  }
  __syncthreads();
  const int w = tid >> 6, l = tid & 63, la = l & 15, gr = l >> 4;
  const int row0 = blockIdx.x * 256 + w * 32;
  if (row0 >= NN) return;
  const bool m1ok = (row0 + 32) <= NN;
  const unsigned short* hb[3] = {h0b, h1b, h2b};
  f32x4 zero = {0.f, 0.f, 0.f, 0.f};
  f32x4 acc[2][8];
#pragma unroll
  for (int m = 0; m < 2; ++m)
#pragma unroll
    for (int nt = 0; nt < 8; ++nt) acc[m][nt] = zero;
#pragma unroll
  for (int p = 0; p < 3; ++p) {
    short8_t a[2][4];
#pragma unroll
    for (int m = 0; m < 2; ++m) {
      const int r = row0 + m * 16 + la;
      const bool ok = (m == 0) || m1ok;
      const unsigned short* ap = hb[p] + (size_t)r * DD + gr * 8;
#pragma unroll
      for (int ks = 0; ks < 4; ++ks)
        a[m][ks] = ok ? *(const short8_t*)(ap + ks * 32) : (short8_t)0;
    }
    const unsigned short* sfp = sF + p * 16384;
#pragma unroll
    for (int nt = 0; nt < 8; ++nt) {
#pragma unroll
      for (int ks = 0; ks < 4; ++ks) {
        short8_t b = *(const short8_t*)(sfp + ((nt * 4 + ks) * 64 + l) * 8);
        acc[0][nt] = __builtin_amdgcn_mfma_f32_16x16x32_bf16(a[0][ks], b, acc[0][nt], 0, 0, 0);
        acc[1][nt] = __builtin_amdgcn_mfma_f32_16x16x32_bf16(a[1][ks], b, acc[1][nt], 0, 0, 0);
      }
    }
  }
#pragma unroll
  for (int m = 0; m < 2; ++m) {
    if (m == 1 && !m1ok) break;
#pragma unroll
    for (int rr = 0; rr < 4; ++rr) {
      const int row = row0 + m * 16 + gr * 4 + rr;
#pragma unroll
      for (int nt = 0; nt < 8; ++nt)
        Y[(size_t)row * DD + nt * 16 + la] = acc[m][nt][rr];
    }
  }
}

// ---------------- bf16 CSR gather, batched over gridDim.y = relations --------
#define ACC8(A, V, C) \
  A[0] = fmaf(bfl((V).x), (C), A[0]); A[1] = fmaf(bfh((V).x), (C), A[1]); \
  A[2] = fmaf(bfl((V).y), (C), A[2]); A[3] = fmaf(bfh((V).y), (C), A[3]); \
  A[4] = fmaf(bfl((V).z), (C), A[4]); A[5] = fmaf(bfh((V).z), (C), A[5]); \
  A[6] = fmaf(bfl((V).w), (C), A[6]); A[7] = fmaf(bfh((V).w), (C), A[7]);

__global__ __launch_bounds__(256) void gatherb_kernel(
    const unsigned short* __restrict__ hb, const int* __restrict__ rowptr,
    const int* __restrict__ col, const float* __restrict__ rsqo,
    unsigned short* __restrict__ ub) {
  const size_t ND = (size_t)NN * DD;
  const int rel = blockIdx.y;
  rowptr += (size_t)rel * (NN + 1);
  col += (size_t)rel * NE;
  rsqo += (size_t)rel * NN;
  ub += (size_t)rel * ND;
  int gid = blockIdx.x * 256 + threadIdx.x;
  int n = gid >> 4;
  int lane = gid & 15;
  int e0 = clampi(rowptr[n], 0, NE);
  int e1 = clampi(rowptr[n + 1], e0, NE);
  const uint4* h4 = (const uint4*)hb;  // row = 16 x uint4 (256B)
  float a[8] = {0, 0, 0, 0, 0, 0, 0, 0}, b[8] = {0, 0, 0, 0, 0, 0, 0, 0};
  float c[8] = {0, 0, 0, 0, 0, 0, 0, 0}, d[8] = {0, 0, 0, 0, 0, 0, 0, 0};
  int e = e0;
  for (; e + 7 < e1; e += 8) {
    int s0 = clampi(col[e], 0, NN - 1), s1 = clampi(col[e + 1], 0, NN - 1);
    int s2 = clampi(col[e + 2], 0, NN - 1), s3 = clampi(col[e + 3], 0, NN - 1);
    int s4 = clampi(col[e + 4], 0, NN - 1), s5 = clampi(col[e + 5], 0, NN - 1);
    int s6 = clampi(col[e + 6], 0, NN - 1), s7 = clampi(col[e + 7], 0, NN - 1);
    float c0 = rsqo[s0], c1 = rsqo[s1], c2 = rsqo[s2], c3 = rsqo[s3];
    float c4 = rsqo[s4], c5 = rsqo[s5], c6 = rsqo[s6], c7 = rsqo[s7];
    uint4 v0 = h4[(size_t)s0 * 16 + lane];
    uint4 v1 = h4[(size_t)s1 * 16 + lane];
    uint4 v2 = h4[(size_t)s2 * 16 + lane];
    uint4 v3 = h4[(size_t)s3 * 16 + lane];
    uint4 v4 = h4[(size_t)s4 * 16 + lane];
    uint4 v5 = h4[(size_t)s5 * 16 + lane];
    uint4 v6 = h4[(size_t)s6 * 16 + lane];
    uint4 v7 = h4[(size_t)s7 * 16 + lane];
    ACC8(a, v0, c0) ACC8(b, v1, c1) ACC8(c, v2, c2) ACC8(d, v3, c3)
    ACC8(a, v4, c4) ACC8(b, v5, c5) ACC8(c, v6, c6) ACC8(d, v7, c7)
  }
  for (; e + 3 < e1; e += 4) {
    int s0 = clampi(col[e], 0, NN - 1), s1 = clampi(col[e + 1], 0, NN - 1);
    int s2 = clampi(col[e + 2], 0, NN - 1), s3 = clampi(col[e + 3], 0, NN - 1);
    float c0 = rsqo[s0], c1 = rsqo[s1], c2 = rsqo[s2], c3 = rsqo[s3];
    uint4 v0 = h4[(size_t)s0 * 16 + lane];
    uint4 v1 = h4[(size_t)s1 * 16 + lane];
    uint4 v2 = h4[(size_t)s2 * 16 + lane];
    uint4 v3 = h4[(size_t)s3 * 16 + lane];
    ACC8(a, v0, c0) ACC8(b, v1, c1) ACC8(c, v2, c2) ACC8(d, v3, c3)
  }
  for (; e < e1; ++e) {
    int s0 = clampi(col[e], 0, NN - 1);
    float c0 = rsqo[s0];
    uint4 v0 = h4[(size_t)s0 * 16 + lane];
    ACC8(a, v0, c0)
  }
#pragma unroll
  for (int j = 0; j < 8; ++j) a[j] += b[j] + c[j] + d[j];
  uint4 o;
  o.x = (unsigned int)f2bf(a[0]) | ((unsigned int)f2bf(a[1]) << 16);
  o.y = (unsigned int)f2bf(a[2]) | ((unsigned int)f2bf(a[3]) << 16);
  o.z = (unsigned int)f2bf(a[4]) | ((unsigned int)f2bf(a[5]) << 16);
  o.w = (unsigned int)f2bf(a[6]) | ((unsigned int)f2bf(a[7]) << 16);
  ((uint4*)ub)[gid] = o;
}

// ------- fused MFMA scores + softmax + combine (Vb read once, in registers) ---
// TWO=1: gridDim.y=2 → y=0: planes 0-2 (l=1, fa1, AQ1, out hout+0);
//                      y=1: planes 3-5 (l=0, fa0, AQ0, out hout+ND).
template <int TWO>
__global__ __launch_bounds__(256) void mscomb_kernel(
    const unsigned short* __restrict__ Vb, const unsigned short* __restrict__ faB,
    const float* __restrict__ AQB, unsigned short* __restrict__ houtB,
    float* __restrict__ attn_out) {
  const size_t ND = (size_t)NN * DD;
  const int y = TWO ? blockIdx.y : 0;
  const unsigned short* Vp = Vb + (TWO ? (size_t)y * 3 * ND : 0);
  const unsigned short* fa = TWO ? faB + (size_t)(1 - y) * 8192 : faB;
  const float* AQ = TWO ? AQB + (size_t)(1 - y) * DQ : AQB;
  unsigned short* houtb = TWO ? houtB + (size_t)y * ND : houtB;
  __shared__ unsigned short sF[8192];  // 16 KB
  __shared__ float sS[4][3][32];
  const int tid = threadIdx.x;
  {
    const float4* s = (const float4*)fa;
    float4* d = (float4*)sF;
#pragma unroll
    for (int i = 0; i < 4; ++i) d[tid + i * 256] = s[tid + i * 256];
  }
  const int w = tid >> 6, l = tid & 63, la = l & 15, gr = l >> 4;
  int row0 = blockIdx.x * 128 + w * 32;
  if (row0 + 32 > NN) row0 = NN - 32;  // clamp (dup rows idempotent), no return
  short8_t a[3][2][4];
#pragma unroll
  for (int r3 = 0; r3 < 3; ++r3) {
#pragma unroll
    for (int m = 0; m < 2; ++m) {
      const unsigned short* rp =
          Vp + (size_t)r3 * ND + (size_t)(row0 + m * 16 + la) * DD + gr * 8;
#pragma unroll
      for (int ks = 0; ks < 4; ++ks)
        a[r3][m][ks] = *(const short8_t*)(rp + ks * 32);
    }
  }
  __syncthreads();  // sF ready
  float q[4];
#pragma unroll
  for (int nt = 0; nt < 4; ++nt) q[nt] = AQ[la + nt * 16];
#pragma unroll
  for (int r3 = 0; r3 < 3; ++r3) {
    f32x4 zero = {0.f, 0.f, 0.f, 0.f};
    f32x4 acc[2][4];
#pragma unroll
    for (int m = 0; m < 2; ++m)
#pragma unroll
      for (int nt = 0; nt < 4; ++nt) acc[m][nt] = zero;
#pragma unroll
    for (int nt = 0; nt < 4; ++nt) {
#pragma unroll
      for (int ks = 0; ks < 4; ++ks) {
        short8_t b = *(const short8_t*)(sF + ((nt * 4 + ks) * 64 + l) * 8);
        acc[0][nt] = __builtin_amdgcn_mfma_f32_16x16x32_bf16(a[r3][0][ks], b, acc[0][nt], 0, 0, 0);
        acc[1][nt] = __builtin_amdgcn_mfma_f32_16x16x32_bf16(a[r3][1][ks], b, acc[1][nt], 0, 0, 0);
      }
    }
#pragma unroll
    for (int m = 0; m < 2; ++m) {
#pragma unroll
      for (int rr = 0; rr < 4; ++rr) {
        float p = tanhf(acc[m][0][rr]) * q[0] + tanhf(acc[m][1][rr]) * q[1] +
                  tanhf(acc[m][2][rr]) * q[2] + tanhf(acc[m][3][rr]) * q[3];
#pragma unroll
        for (int off = 1; off < 16; off <<= 1) p += __shfl_xor(p, off, 16);
        if (la == 0) sS[w][r3][m * 16 + gr * 4 + rr] = p;
      }
    }
  }
  __syncthreads();
#pragma unroll
  for (int m = 0; m < 2; ++m) {
    const int row = row0 + m * 16 + la;
    float s0 = sS[w][0][m * 16 + la];
    float s1 = sS[w][1][m * 16 + la];
    float s2 = sS[w][2][m * 16 + la];
    float mx = fmaxf(s0, fmaxf(s1, s2));
    float e0 = __expf(s0 - mx), e1 = __expf(s1 - mx), e2 = __expf(s2 - mx);
    float inv = 1.0f / (e0 + e1 + e2);
    float a0 = e0 * inv, a1 = e1 * inv, a2 = e2 * inv;
#pragma unroll
    for (int ks = 0; ks < 4; ++ks) {
      unsigned int ow[4];
#pragma unroll
      for (int jj = 0; jj < 4; ++jj) {
        float v0 = a0 * b2f(a[0][m][ks][2 * jj]) + a1 * b2f(a[1][m][ks][2 * jj]) +
                   a2 * b2f(a[2][m][ks][2 * jj]);
        float v1 = a0 * b2f(a[0][m][ks][2 * jj + 1]) + a1 * b2f(a[1][m][ks][2 * jj + 1]) +
                   a2 * b2f(a[2][m][ks][2 * jj + 1]);
        ow[jj] = (unsigned int)f2bf(v0) | ((unsigned int)f2bf(v1) << 16);
      }
      *(uint4*)(houtb + (size_t)row * DD + gr * 8 + ks * 32) =
          make_uint4(ow[0], ow[1], ow[2], ow[3]);
    }
    if (attn_out != nullptr) {
      attn_out[(size_t)row * 3 + 0] = a0;
      attn_out[(size_t)row * 3 + 1] = a1;
      attn_out[(size_t)row * 3 + 2] = a2;
    }
  }
}

extern "C" void kernel_launch(void* const* d_in, const int* in_sizes, int n_in,
                              void* d_out, int out_size, void* d_ws, size_t ws_size,
                              hipStream_t stream) {
  const float* x        = (const float*)d_in[0];
  const int*   edges    = (const int*)d_in[1];
  const float* feat_w   = (const float*)d_in[2];
  const float* conv_w   = (const float*)d_in[3];
  const float* conv_b   = (const float*)d_in[4];
  const float* attn_w   = (const float*)d_in[5];
  const float* attn_q   = (const float*)d_in[6];
  const float* concat_w = (const float*)d_in[7];
  float* out = (float*)d_out;   // [NN*128 y][NN*3 attn]

  float* ws = (float*)d_ws;
  float* rsqo = ws;                   // [3][NN]
  float* rsqi = rsqo + 3 * NN;        // [3][NN]
  int* btot = (int*)(rsqi + 3 * NN);  // 80 ints
  int* boff = btot + 80;              // 80 ints
  int* cnt = boff + 96;               // spare region; fw overlays here
  int* rowptr = cnt + 3 * NN;         // [3][NN+1] (+pad)
  int* col = rowptr + 3 * (NN + 1) + 13;  // [3][NE]
  const size_t ND = (size_t)NN * DD;
  float* P1 = (float*)(col + 3 * (size_t)NE);  // prologue: rank8 | VbAll 0-1
  float* PA = P1 + ND;   // prologue: hist | VbAll planes 2-3
  float* PB = PA + ND;   // prologue: delta8 | VbAll planes 4-5
  unsigned short* U0 = (unsigned short*)(PB + ND);  // u bf16 x3; later h2b
  unsigned short* B0 = U0 + 3 * ND;   // h0b
  unsigned short* B1 = B0 + ND;       // h1b
  unsigned short* B2 = B1 + ND;       // tb
  unsigned short* fw = (unsigned short*)cnt;   // 10x16384 + 2x8192 ushort
  unsigned int* hist = (unsigned int*)PA;      // [6][NB][NWW] = 12.6 MB <= plane
  unsigned char* delta8 = (unsigned char*)PB;  // [3][NB][NN] = 6.3 MB <= plane
  unsigned char* rank8 = (unsigned char*)P1;   // [3][NE] = 2.4 MB <= plane
  unsigned short* VbAll = (unsigned short*)P1; // 6 bf16 vals planes (contig)
  unsigned short* fa0 = fw + (size_t)10 * 16384;
  unsigned short* fa1 = fa0 + 8192;

  // prologue: degrees + CSR (no global atomics; byte-packed 50KB LDS hist)
  hist6_kernel<<<dim3(NB, 6), 512, 0, stream>>>(edges, hist, rank8);
  sumscan_kernel<<<dim3(25, 6), 256, 0, stream>>>(hist, rowptr, btot, rsqi, rsqo);
  scanp2_kernel<<<1, 64, 0, stream>>>(btot, boff, rowptr);
  prepw_kernel<<<12, 256, 0, stream>>>(conv_w, feat_w, concat_w, attn_w, fw);
  bases_kernel<<<dim3(25, 3), 256, 0, stream>>>(hist, boff, rowptr, (unsigned int*)delta8);
  fillr_kernel<<<dim3(3125, 3), 256, 0, stream>>>(edges, rank8, delta8, rowptr, col);

  // h0 = tanh(x @ feat_w) -> B0 bf16
  mgemm_kernel<1, 1, 0, 0><<<dim3(391, 1), 256, 0, stream>>>(
      x, fw + (size_t)6 * 16384, nullptr, nullptr, nullptr, B0);

  // shared u[r] = A_r^T (h0 * rsqo_r) -> U planes, batched
  gatherb_kernel<<<dim3(3125, 3), 256, 0, stream>>>(B0, rowptr, col, rsqo, U0);

  // both h0-fed layers in one launch: planes 0-2 = l1 vals, 3-5 = l0 vals
  mgemm_kernel<0, 0, 1, 1><<<dim3(391, 6), 256, 0, stream>>>(
      U0, fw, rsqi, conv_b, B0, VbAll);
  // both mscombs in one launch: h1 -> B1, t -> B2
  mscomb_kernel<1><<<dim3(391, 2), 256, 0, stream>>>(
      VbAll, fa0, attn_q, B1, nullptr);

  // layer l=1 on t: gathers from B2 -> U; convs (resid = B2) -> planes 0-2
  gatherb_kernel<<<dim3(3125, 3), 256, 0, stream>>>(B2, rowptr, col, rsqo, U0);
  mgemm_kernel<0, 0, 1, 0><<<dim3(391, 3), 256, 0, stream>>>(
      U0, fw + (size_t)3 * 16384, rsqi, conv_b + (size_t)3 * DD, B2, VbAll);
  // h2 -> U0 (bf16), attn -> out+ND
  mscomb_kernel<0><<<dim3(391, 1), 256, 0, stream>>>(
      VbAll, fa1, attn_q + DQ, U0, out + ND);

  // y = [h0|h1|h2] @ CW^T -> out
  mconcat_kernel<<<196, 512, 0, stream>>>(B0, B1, U0, fw + (size_t)7 * 16384, out);
}

// Round 14
// 422.185 us; speedup vs baseline: 1.0984x; 1.0117x over previous
//
#include <hip/hip_runtime.h>

#define NN 50000
#define NE 800000
#define DD 128
#define DQ 64
#define NB 42          // histogram/fill blocks per (relation, array)
#define SL 19048       // edge slice per block: 42*19048 >= NE
#define NWW 12500      // packed uint8x4 words covering NN counters

typedef __attribute__((ext_vector_type(8))) short short8_t;  // 8 bf16 (4 VGPR)
typedef __attribute__((ext_vector_type(4))) float f32x4;     // MFMA acc

__device__ __forceinline__ int clampi(int v, int lo, int hi) {
  return v < lo ? lo : (v > hi ? hi : v);
}
__device__ __forceinline__ unsigned short f2bf(float f) {  // RNE fp32->bf16
  unsigned int u = __float_as_uint(f);
  return (unsigned short)((u + 0x7FFFu + ((u >> 16) & 1u)) >> 16);
}
__device__ __forceinline__ float bfl(unsigned int u) { return __uint_as_float(u << 16); }
__device__ __forceinline__ float bfh(unsigned int u) { return __uint_as_float(u & 0xFFFF0000u); }
__device__ __forceinline__ float b2f(short s) {
  return __uint_as_float(((unsigned int)(unsigned short)s) << 16);
}

// ---------------- prologue (edges int32 per harness contract) ----------------
// grid (42, 7). y<6: per-block LDS histograms, 4x uint8 packed per word; dst
// combos (even y) also emit each edge's local rank (uint8). y==6 (x<12): weight
// fragment prep rides along as extra blocks (saves a launch).
__global__ __launch_bounds__(512) void hist6_kernel(
    const int* __restrict__ e, unsigned int* __restrict__ hist,
    unsigned char* __restrict__ rank,
    const float* __restrict__ conv_w, const float* __restrict__ feat_w,
    const float* __restrict__ concat_w, const float* __restrict__ attn_w,
    unsigned short* __restrict__ fw) {
  __shared__ unsigned int lds[NWW];  // 50 KB -> 2 blocks/CU
  const int c = blockIdx.y;
  const int tid = threadIdx.x;
  if (c == 6) {  // ---- prepw blocks ----
    const int i = blockIdx.x;
    if (i >= 12) return;
    if (i < 10) {
      unsigned short* dst = fw + (size_t)i * 16384;
      for (int eI = tid; eI < 2048; eI += 512) {
        int nt = eI >> 8, ks = (eI >> 6) & 3, lane = eI & 63;
        int n = (lane & 15) + nt * 16;
        int kb = (lane >> 4) * 8 + ks * 32;
        unsigned int w[4];
#pragma unroll
        for (int jj = 0; jj < 4; ++jj) {
          int k0 = kb + 2 * jj, k1 = k0 + 1;
          float f0, f1;
          if (i < 6) {
            f0 = conv_w[(size_t)i * 16384 + (size_t)k0 * DD + n];
            f1 = conv_w[(size_t)i * 16384 + (size_t)k1 * DD + n];
          } else if (i == 6) {
            f0 = feat_w[(size_t)k0 * DD + n];
            f1 = feat_w[(size_t)k1 * DD + n];
          } else {
            int p = i - 7;
            f0 = concat_w[(size_t)n * 384 + p * DD + k0];
            f1 = concat_w[(size_t)n * 384 + p * DD + k1];
          }
          w[jj] = (unsigned int)f2bf(f0) | ((unsigned int)f2bf(f1) << 16);
        }
        ((uint4*)dst)[eI] = make_uint4(w[0], w[1], w[2], w[3]);
      }
    } else {
      const int l = i - 10;
      unsigned short* dst = fw + (size_t)10 * 16384 + (size_t)l * 8192;
      for (int eI = tid; eI < 1024; eI += 512) {
        int nt = eI >> 8, ks = (eI >> 6) & 3, lane = eI & 63;  // nt 0..3
        int n = (lane & 15) + nt * 16;
        int kb = (lane >> 4) * 8 + ks * 32;
        unsigned int w[4];
#pragma unroll
        for (int jj = 0; jj < 4; ++jj) {
          int k0 = kb + 2 * jj, k1 = k0 + 1;
          float f0 = attn_w[((size_t)l * DD + k0) * DQ + n];
          float f1 = attn_w[((size_t)l * DD + k1) * DQ + n];
          w[jj] = (unsigned int)f2bf(f0) | ((unsigned int)f2bf(f1) << 16);
        }
        ((uint4*)dst)[eI] = make_uint4(w[0], w[1], w[2], w[3]);
      }
    }
    return;
  }
  // ---- histogram blocks ----
  const int b = blockIdx.x;
  const int r = c >> 1;
  const int a = c & 1;  // 0: dst (rank emitted), 1: src
  for (int i = tid; i < NWW; i += 512) lds[i] = 0u;
  __syncthreads();
  const size_t abase = (size_t)r * 2 * NE + (a ? 0 : NE);
  const int beg = b * SL, end = min(beg + SL, NE);
  if (a == 0) {
    unsigned char* rk = rank + (size_t)r * NE;
    for (int i = beg + tid; i < end; i += 512) {
      int v = clampi(e[abase + i], 0, NN - 1);
      unsigned int sh = (v & 3) * 8;
      unsigned int old = atomicAdd(&lds[v >> 2], 1u << sh);
      rk[i] = (unsigned char)((old >> sh) & 0xFFu);
    }
  } else {
    for (int i = beg + tid; i < end; i += 512) {
      int v = clampi(e[abase + i], 0, NN - 1);
      atomicAdd(&lds[v >> 2], 1u << ((v & 3) * 8));
    }
  }
  __syncthreads();
  unsigned int* outp = hist + ((size_t)c * NB + b) * NWW;
  for (int i = tid; i < NWW; i += 512) outp[i] = lds[i];
}

// Merged sumhist + local scan. grid (25, 6): block (g,c) covers words
// [g*500, +500) = nodes [g*2000, +2000). a=0: counts -> rsqi + local prefix
// into rowptr (block-LOCAL) + btot. a=1: rsqo only.
__global__ __launch_bounds__(256) void sumscan_kernel(
    const unsigned int* __restrict__ hist, int* __restrict__ rowptr,
    int* __restrict__ btot, float* __restrict__ rsqi, float* __restrict__ rsqo) {
  __shared__ int part[256];
  const int g = blockIdx.x;
  const int c = blockIdx.y;
  const int r = c >> 1, a = c & 1;
  const int t = threadIdx.x;
  int cntv[8];
  int s = 0;
  const int w0 = g * 500 + t * 2;
  if (t < 250) {
#pragma unroll
    for (int j = 0; j < 2; ++j) {
      const unsigned int* hp = hist + (size_t)c * NB * NWW + w0 + j;
      unsigned int accA = 0, accB = 0;  // fields: (b0,b2) and (b1,b3), 16b each
#pragma unroll 6
      for (int b = 0; b < NB; ++b) {
        unsigned int v = hp[(size_t)b * NWW];
        accA += v & 0x00FF00FFu;
        accB += (v >> 8) & 0x00FF00FFu;
      }
      int c0 = (int)(accA & 0xFFFFu), c2 = (int)(accA >> 16);
      int c1 = (int)(accB & 0xFFFFu), c3 = (int)(accB >> 16);
      cntv[4 * j + 0] = c0; cntv[4 * j + 1] = c1;
      cntv[4 * j + 2] = c2; cntv[4 * j + 3] = c3;
      int n0 = 4 * (w0 + j);
      float* rq = (a == 0) ? rsqi : rsqo;
      rq[r * NN + n0 + 0] = rsqrtf(fmaxf((float)c0, 1.0f));
      rq[r * NN + n0 + 1] = rsqrtf(fmaxf((float)c1, 1.0f));
      rq[r * NN + n0 + 2] = rsqrtf(fmaxf((float)c2, 1.0f));
      rq[r * NN + n0 + 3] = rsqrtf(fmaxf((float)c3, 1.0f));
      s += c0 + c1 + c2 + c3;
    }
  }
  if (a == 1) return;  // block-uniform: src combos skip the scan
  part[t] = s;
  __syncthreads();
  for (int off = 1; off < 256; off <<= 1) {
    int x = (t >= off) ? part[t - off] : 0;
    __syncthreads();
    part[t] += x;
    __syncthreads();
  }
  if (t < 250) {
    int excl = part[t] - s;
    int base = g * 2000 + t * 8;
#pragma unroll
    for (int j = 0; j < 8; ++j) {
      rowptr[r * (NN + 1) + base + j] = excl;  // block-LOCAL for now
      excl += cntv[j];
    }
  }
  if (t == 255) btot[r * 25 + g] = part[255];
}

// Finalize rowptr IN PLACE (local + block offset, computed from btot inline —
// scanp2 launch eliminated) and emit packed uint8 per-histblock deltas.
// Block g==24 also writes rowptr[NN].
__global__ __launch_bounds__(256) void bases_kernel(
    const unsigned int* __restrict__ hist, const int* __restrict__ btot,
    int* __restrict__ rowptr, unsigned int* __restrict__ delta32) {
  const int r = blockIdx.y;
  const int g = blockIdx.x;
  int run = 0, off = 0;
#pragma unroll
  for (int b2 = 0; b2 < 25; ++b2) {
    if (b2 == g) off = run;
    run += btot[r * 25 + b2];
  }
  if (g == 24 && threadIdx.x == 0) rowptr[r * (NN + 1) + NN] = run;
  for (int wl = threadIdx.x; wl < 500; wl += 256) {
    int wi = g * 500 + wl;
    int n0 = 4 * wi;
#pragma unroll
    for (int k = 0; k < 4; ++k) rowptr[r * (NN + 1) + n0 + k] += off;
    const unsigned int* hp = hist + (size_t)(r * 2) * NB * NWW + wi;
    unsigned int runp = 0;  // 4 packed uint8 running prefixes
#pragma unroll 6
    for (int b = 0; b < NB; ++b) {
      delta32[((size_t)r * NB + b) * NWW + wi] = runp;
      runp += hp[(size_t)b * NWW];  // carry-free: fields stay < 256
    }
  }
}

// Fused: y<3 -> streaming CSR fill; y==3 (x<391) -> feat mgemm
// (h0 = tanh(x @ feat_w) -> B0 bf16). Independent work, overlapped tails.
__global__ __launch_bounds__(256) void fillfeat_kernel(
    const int* __restrict__ e, const unsigned char* __restrict__ rank,
    const unsigned char* __restrict__ delta8, const int* __restrict__ rowptr,
    int* __restrict__ col,
    const float* __restrict__ x, const unsigned short* __restrict__ fwfeat,
    unsigned short* __restrict__ B0) {
  __shared__ unsigned short sF[16384];  // used by feat branch only (32 KB)
  const int tid = threadIdx.x;
  if (blockIdx.y < 3) {  // ---- fillr ----
    const int r = blockIdx.y;
    const int i = blockIdx.x * 256 + tid;
    const size_t sbase = (size_t)r * 2 * NE;
    int s = clampi(e[sbase + i], 0, NN - 1);
    int d = clampi(e[sbase + NE + i], 0, NN - 1);
    int b = i / SL;
    int pos = rowptr[r * (NN + 1) + d] +
              (int)delta8[((size_t)r * NB + b) * NN + d] +
              (int)rank[(size_t)r * NE + i];
    pos = clampi(pos, 0, NE - 1);
    col[(size_t)r * NE + pos] = s;
    return;
  }
  // ---- feat mgemm (AFP32=1, TANH=1) ----
  if (blockIdx.x >= 391) return;
  {
    const float4* s = (const float4*)fwfeat;
    float4* d = (float4*)sF;
#pragma unroll
    for (int i = 0; i < 8; ++i) d[tid + i * 256] = s[tid + i * 256];
  }
  __syncthreads();
  const int w = tid >> 6, l = tid & 63, la = l & 15, gr = l >> 4;
  const int row0 = blockIdx.x * 128 + w * 32;
  if (row0 >= NN) return;  // after barrier: safe
  const bool m1ok = (row0 + 32) <= NN;
  short8_t a[2][4];
#pragma unroll
  for (int m = 0; m < 2; ++m) {
    const int r = row0 + m * 16 + la;
    const bool ok = (m == 0) || m1ok;
    const float* ap = x + (size_t)r * DD + gr * 8;
#pragma unroll
    for (int ks = 0; ks < 4; ++ks) {
      short8_t v = (short8_t)0;
      if (ok) {
        float4 x0 = *(const float4*)(ap + ks * 32);
        float4 x1 = *(const float4*)(ap + ks * 32 + 4);
        v[0] = (short)f2bf(x0.x); v[1] = (short)f2bf(x0.y);
        v[2] = (short)f2bf(x0.z); v[3] = (short)f2bf(x0.w);
        v[4] = (short)f2bf(x1.x); v[5] = (short)f2bf(x1.y);
        v[6] = (short)f2bf(x1.z); v[7] = (short)f2bf(x1.w);
      }
      a[m][ks] = v;
    }
  }
  f32x4 zero = {0.f, 0.f, 0.f, 0.f};
  f32x4 acc[2][8];
#pragma unroll
  for (int m = 0; m < 2; ++m)
#pragma unroll
    for (int nt = 0; nt < 8; ++nt) acc[m][nt] = zero;
#pragma unroll
  for (int nt = 0; nt < 8; ++nt) {
#pragma unroll
    for (int ks = 0; ks < 4; ++ks) {
      short8_t b = *(const short8_t*)(sF + ((nt * 4 + ks) * 64 + l) * 8);
      acc[0][nt] = __builtin_amdgcn_mfma_f32_16x16x32_bf16(a[0][ks], b, acc[0][nt], 0, 0, 0);
      acc[1][nt] = __builtin_amdgcn_mfma_f32_16x16x32_bf16(a[1][ks], b, acc[1][nt], 0, 0, 0);
    }
  }
#pragma unroll
  for (int m = 0; m < 2; ++m) {
    if (m == 1 && !m1ok) break;
#pragma unroll
    for (int rr = 0; rr < 4; ++rr) {
      const int row = row0 + m * 16 + gr * 4 + rr;
#pragma unroll
      for (int nt = 0; nt < 8; ++nt)
        B0[(size_t)row * DD + nt * 16 + la] = f2bf(tanhf(acc[m][nt][rr]));
    }
  }
}

// ---------------- MFMA GEMM: Cb = bf16([tanh](A @ W) [*rsqi + bias + residb]) --
template <int AFP32, int TANH, int EPI, int SIX>
__global__ __launch_bounds__(256) void mgemm_kernel(
    const void* __restrict__ Ap, const unsigned short* __restrict__ fw,
    const float* __restrict__ rsqi, const float* __restrict__ bias,
    const unsigned short* __restrict__ residb, unsigned short* __restrict__ Cb) {
  const size_t ND = (size_t)NN * DD;
  const int rel = blockIdx.y;
  const int wsel = SIX ? (rel + 3) % 6 : rel;
  const int arel = SIX ? rel % 3 : rel;
  const unsigned short* fwp = fw + (size_t)wsel * 16384;
  const float* rsqip = EPI ? rsqi + (size_t)arel * NN : nullptr;
  const float* biasp = EPI ? bias + (size_t)wsel * DD : nullptr;
  unsigned short* Cbp = Cb + (size_t)rel * ND;
  __shared__ unsigned short sF[16384];  // 32 KB
  const int tid = threadIdx.x;
  {
    const float4* s = (const float4*)fwp;
    float4* d = (float4*)sF;
#pragma unroll
    for (int i = 0; i < 8; ++i) d[tid + i * 256] = s[tid + i * 256];
  }
  __syncthreads();
  const int w = tid >> 6, l = tid & 63, la = l & 15, gr = l >> 4;
  const int row0 = blockIdx.x * 128 + w * 32;
  if (row0 >= NN) return;  // after barrier: safe
  const bool m1ok = (row0 + 32) <= NN;  // NN % 16 == 0
  short8_t a[2][4];
#pragma unroll
  for (int m = 0; m < 2; ++m) {
    const int r = row0 + m * 16 + la;
    const bool ok = (m == 0) || m1ok;
    if (AFP32) {
      const float* ap = (const float*)Ap + (size_t)r * DD + gr * 8;
#pragma unroll
      for (int ks = 0; ks < 4; ++ks) {
        short8_t v = (short8_t)0;
        if (ok) {
          float4 x0 = *(const float4*)(ap + ks * 32);
          float4 x1 = *(const float4*)(ap + ks * 32 + 4);
          v[0] = (short)f2bf(x0.x); v[1] = (short)f2bf(x0.y);
          v[2] = (short)f2bf(x0.z); v[3] = (short)f2bf(x0.w);
          v[4] = (short)f2bf(x1.x); v[5] = (short)f2bf(x1.y);
          v[6] = (short)f2bf(x1.z); v[7] = (short)f2bf(x1.w);
        }
        a[m][ks] = v;
      }
    } else {
      const unsigned short* ap =
          (const unsigned short*)Ap + (size_t)arel * ND + (size_t)r * DD + gr * 8;
#pragma unroll
      for (int ks = 0; ks < 4; ++ks)
        a[m][ks] = ok ? *(const short8_t*)(ap + ks * 32) : (short8_t)0;
    }
  }
  f32x4 zero = {0.f, 0.f, 0.f, 0.f};
  f32x4 acc[2][8];
#pragma unroll
  for (int m = 0; m < 2; ++m)
#pragma unroll
    for (int nt = 0; nt < 8; ++nt) acc[m][nt] = zero;
#pragma unroll
  for (int nt = 0; nt < 8; ++nt) {
#pragma unroll
    for (int ks = 0; ks < 4; ++ks) {
      short8_t b = *(const short8_t*)(sF + ((nt * 4 + ks) * 64 + l) * 8);
      acc[0][nt] = __builtin_amdgcn_mfma_f32_16x16x32_bf16(a[0][ks], b, acc[0][nt], 0, 0, 0);
      acc[1][nt] = __builtin_amdgcn_mfma_f32_16x16x32_bf16(a[1][ks], b, acc[1][nt], 0, 0, 0);
    }
  }
#pragma unroll
  for (int m = 0; m < 2; ++m) {
    if (m == 1 && !m1ok) break;
#pragma unroll
    for (int rr = 0; rr < 4; ++rr) {
      const int row = row0 + m * 16 + gr * 4 + rr;
      const float sc = EPI ? rsqip[row] : 0.0f;
#pragma unroll
      for (int nt = 0; nt < 8; ++nt) {
        const int c0 = nt * 16 + la;
        float v = acc[m][nt][rr];
        if (TANH) v = tanhf(v);
        if (EPI) {
          float rv = __uint_as_float((unsigned int)residb[(size_t)row * DD + c0] << 16);
          v = fmaf(v, sc, biasp[c0] + rv);
        }
        Cbp[(size_t)row * DD + c0] = f2bf(v);
      }
    }
  }
}

// ---------------- MFMA concat: y = sum_p hb[p] @ Bp (K=384) ----------------
__global__ __launch_bounds__(512) void mconcat_kernel(
    const unsigned short* __restrict__ h0b, const unsigned short* __restrict__ h1b,
    const unsigned short* __restrict__ h2b, const unsigned short* __restrict__ fwc,
    float* __restrict__ Y) {
  __shared__ unsigned short sF[3 * 16384];  // 96 KB
  const int tid = threadIdx.x;
  {
    const float4* s = (const float4*)fwc;
    float4* d = (float4*)sF;
#pragma unroll
    for (int i = 0; i < 12; ++i) d[tid + i * 512] = s[tid + i * 512];
  }
  __syncthreads();
  const int w = tid >> 6, l = tid & 63, la = l & 15, gr = l >> 4;
  const int row0 = blockIdx.x * 256 + w * 32;
  if (row0 >= NN) return;
  const bool m1ok = (row0 + 32) <= NN;
  const unsigned short* hb[3] = {h0b, h1b, h2b};
  f32x4 zero = {0.f, 0.f, 0.f, 0.f};
  f32x4 acc[2][8];
#pragma unroll
  for (int m = 0; m < 2; ++m)
#pragma unroll
    for (int nt = 0; nt < 8; ++nt) acc[m][nt] = zero;
#pragma unroll
  for (int p = 0; p < 3; ++p) {
    short8_t a[2][4];
#pragma unroll
    for (int m = 0; m < 2; ++m) {
      const int r = row0 + m * 16 + la;
      const bool ok = (m == 0) || m1ok;
      const unsigned short* ap = hb[p] + (size_t)r * DD + gr * 8;
#pragma unroll
      for (int ks = 0; ks < 4; ++ks)
        a[m][ks] = ok ? *(const short8_t*)(ap + ks * 32) : (short8_t)0;
    }
    const unsigned short* sfp = sF + p * 16384;
#pragma unroll
    for (int nt = 0; nt < 8; ++nt) {
#pragma unroll
      for (int ks = 0; ks < 4; ++ks) {
        short8_t b = *(const short8_t*)(sfp + ((nt * 4 + ks) * 64 + l) * 8);
        acc[0][nt] = __builtin_amdgcn_mfma_f32_16x16x32_bf16(a[0][ks], b, acc[0][nt], 0, 0, 0);
        acc[1][nt] = __builtin_amdgcn_mfma_f32_16x16x32_bf16(a[1][ks], b, acc[1][nt], 0, 0, 0);
      }
    }
  }
#pragma unroll
  for (int m = 0; m < 2; ++m) {
    if (m == 1 && !m1ok) break;
#pragma unroll
    for (int rr = 0; rr < 4; ++rr) {
      const int row = row0 + m * 16 + gr * 4 + rr;
#pragma unroll
      for (int nt = 0; nt < 8; ++nt)
        Y[(size_t)row * DD + nt * 16 + la] = acc[m][nt][rr];
    }
  }
}

// ---------------- bf16 CSR gather, batched over gridDim.y = relations --------
#define ACC8(A, V, C) \
  A[0] = fmaf(bfl((V).x), (C), A[0]); A[1] = fmaf(bfh((V).x), (C), A[1]); \
  A[2] = fmaf(bfl((V).y), (C), A[2]); A[3] = fmaf(bfh((V).y), (C), A[3]); \
  A[4] = fmaf(bfl((V).z), (C), A[4]); A[5] = fmaf(bfh((V).z), (C), A[5]); \
  A[6] = fmaf(bfl((V).w), (C), A[6]); A[7] = fmaf(bfh((V).w), (C), A[7]);

__global__ __launch_bounds__(256) void gatherb_kernel(
    const unsigned short* __restrict__ hb, const int* __restrict__ rowptr,
    const int* __restrict__ col, const float* __restrict__ rsqo,
    unsigned short* __restrict__ ub) {
  const size_t ND = (size_t)NN * DD;
  const int rel = blockIdx.y;
  rowptr += (size_t)rel * (NN + 1);
  col += (size_t)rel * NE;
  rsqo += (size_t)rel * NN;
  ub += (size_t)rel * ND;
  int gid = blockIdx.x * 256 + threadIdx.x;
  int n = gid >> 4;
  int lane = gid & 15;
  int e0 = clampi(rowptr[n], 0, NE);
  int e1 = clampi(rowptr[n + 1], e0, NE);
  const uint4* h4 = (const uint4*)hb;  // row = 16 x uint4 (256B)
  float a[8] = {0, 0, 0, 0, 0, 0, 0, 0}, b[8] = {0, 0, 0, 0, 0, 0, 0, 0};
  float c[8] = {0, 0, 0, 0, 0, 0, 0, 0}, d[8] = {0, 0, 0, 0, 0, 0, 0, 0};
  int e = e0;
  for (; e + 7 < e1; e += 8) {
    int s0 = clampi(col[e], 0, NN - 1), s1 = clampi(col[e + 1], 0, NN - 1);
    int s2 = clampi(col[e + 2], 0, NN - 1), s3 = clampi(col[e + 3], 0, NN - 1);
    int s4 = clampi(col[e + 4], 0, NN - 1), s5 = clampi(col[e + 5], 0, NN - 1);
    int s6 = clampi(col[e + 6], 0, NN - 1), s7 = clampi(col[e + 7], 0, NN - 1);
    float c0 = rsqo[s0], c1 = rsqo[s1], c2 = rsqo[s2], c3 = rsqo[s3];
    float c4 = rsqo[s4], c5 = rsqo[s5], c6 = rsqo[s6], c7 = rsqo[s7];
    uint4 v0 = h4[(size_t)s0 * 16 + lane];
    uint4 v1 = h4[(size_t)s1 * 16 + lane];
    uint4 v2 = h4[(size_t)s2 * 16 + lane];
    uint4 v3 = h4[(size_t)s3 * 16 + lane];
    uint4 v4 = h4[(size_t)s4 * 16 + lane];
    uint4 v5 = h4[(size_t)s5 * 16 + lane];
    uint4 v6 = h4[(size_t)s6 * 16 + lane];
    uint4 v7 = h4[(size_t)s7 * 16 + lane];
    ACC8(a, v0, c0) ACC8(b, v1, c1) ACC8(c, v2, c2) ACC8(d, v3, c3)
    ACC8(a, v4, c4) ACC8(b, v5, c5) ACC8(c, v6, c6) ACC8(d, v7, c7)
  }
  for (; e + 3 < e1; e += 4) {
    int s0 = clampi(col[e], 0, NN - 1), s1 = clampi(col[e + 1], 0, NN - 1);
    int s2 = clampi(col[e + 2], 0, NN - 1), s3 = clampi(col[e + 3], 0, NN - 1);
    float c0 = rsqo[s0], c1 = rsqo[s1], c2 = rsqo[s2], c3 = rsqo[s3];
    uint4 v0 = h4[(size_t)s0 * 16 + lane];
    uint4 v1 = h4[(size_t)s1 * 16 + lane];
    uint4 v2 = h4[(size_t)s2 * 16 + lane];
    uint4 v3 = h4[(size_t)s3 * 16 + lane];
    ACC8(a, v0, c0) ACC8(b, v1, c1) ACC8(c, v2, c2) ACC8(d, v3, c3)
  }
  for (; e < e1; ++e) {
    int s0 = clampi(col[e], 0, NN - 1);
    float c0 = rsqo[s0];
    uint4 v0 = h4[(size_t)s0 * 16 + lane];
    ACC8(a, v0, c0)
  }
#pragma unroll
  for (int j = 0; j < 8; ++j) a[j] += b[j] + c[j] + d[j];
  uint4 o;
  o.x = (unsigned int)f2bf(a[0]) | ((unsigned int)f2bf(a[1]) << 16);
  o.y = (unsigned int)f2bf(a[2]) | ((unsigned int)f2bf(a[3]) << 16);
  o.z = (unsigned int)f2bf(a[4]) | ((unsigned int)f2bf(a[5]) << 16);
  o.w = (unsigned int)f2bf(a[6]) | ((unsigned int)f2bf(a[7]) << 16);
  ((uint4*)ub)[gid] = o;
}

// ------- fused MFMA scores + softmax + combine (Vb read once, in registers) ---
// TWO=1: gridDim.y=2 → y=0: planes 0-2 (l=1, fa1, AQ1, out hout+0);
//                      y=1: planes 3-5 (l=0, fa0, AQ0, out hout+ND).
template <int TWO>
__global__ __launch_bounds__(256) void mscomb_kernel(
    const unsigned short* __restrict__ Vb, const unsigned short* __restrict__ faB,
    const float* __restrict__ AQB, unsigned short* __restrict__ houtB,
    float* __restrict__ attn_out) {
  const size_t ND = (size_t)NN * DD;
  const int y = TWO ? blockIdx.y : 0;
  const unsigned short* Vp = Vb + (TWO ? (size_t)y * 3 * ND : 0);
  const unsigned short* fa = TWO ? faB + (size_t)(1 - y) * 8192 : faB;
  const float* AQ = TWO ? AQB + (size_t)(1 - y) * DQ : AQB;
  unsigned short* houtb = TWO ? houtB + (size_t)y * ND : houtB;
  __shared__ unsigned short sF[8192];  // 16 KB
  __shared__ float sS[4][3][32];
  const int tid = threadIdx.x;
  {
    const float4* s = (const float4*)fa;
    float4* d = (float4*)sF;
#pragma unroll
    for (int i = 0; i < 4; ++i) d[tid + i * 256] = s[tid + i * 256];
  }
  const int w = tid >> 6, l = tid & 63, la = l & 15, gr = l >> 4;
  int row0 = blockIdx.x * 128 + w * 32;
  if (row0 + 32 > NN) row0 = NN - 32;  // clamp (dup rows idempotent), no return
  short8_t a[3][2][4];
#pragma unroll
  for (int r3 = 0; r3 < 3; ++r3) {
#pragma unroll
    for (int m = 0; m < 2; ++m) {
      const unsigned short* rp =
          Vp + (size_t)r3 * ND + (size_t)(row0 + m * 16 + la) * DD + gr * 8;
#pragma unroll
      for (int ks = 0; ks < 4; ++ks)
        a[r3][m][ks] = *(const short8_t*)(rp + ks * 32);
    }
  }
  __syncthreads();  // sF ready
  float q[4];
#pragma unroll
  for (int nt = 0; nt < 4; ++nt) q[nt] = AQ[la + nt * 16];
#pragma unroll
  for (int r3 = 0; r3 < 3; ++r3) {
    f32x4 zero = {0.f, 0.f, 0.f, 0.f};
    f32x4 acc[2][4];
#pragma unroll
    for (int m = 0; m < 2; ++m)
#pragma unroll
      for (int nt = 0; nt < 4; ++nt) acc[m][nt] = zero;
#pragma unroll
    for (int nt = 0; nt < 4; ++nt) {
#pragma unroll
      for (int ks = 0; ks < 4; ++ks) {
        short8_t b = *(const short8_t*)(sF + ((nt * 4 + ks) * 64 + l) * 8);
        acc[0][nt] = __builtin_amdgcn_mfma_f32_16x16x32_bf16(a[r3][0][ks], b, acc[0][nt], 0, 0, 0);
        acc[1][nt] = __builtin_amdgcn_mfma_f32_16x16x32_bf16(a[r3][1][ks], b, acc[1][nt], 0, 0, 0);
      }
    }
#pragma unroll
    for (int m = 0; m < 2; ++m) {
#pragma unroll
      for (int rr = 0; rr < 4; ++rr) {
        float p = tanhf(acc[m][0][rr]) * q[0] + tanhf(acc[m][1][rr]) * q[1] +
                  tanhf(acc[m][2][rr]) * q[2] + tanhf(acc[m][3][rr]) * q[3];
#pragma unroll
        for (int off = 1; off < 16; off <<= 1) p += __shfl_xor(p, off, 16);
        if (la == 0) sS[w][r3][m * 16 + gr * 4 + rr] = p;
      }
    }
  }
  __syncthreads();
#pragma unroll
  for (int m = 0; m < 2; ++m) {
    const int row = row0 + m * 16 + la;
    float s0 = sS[w][0][m * 16 + la];
    float s1 = sS[w][1][m * 16 + la];
    float s2 = sS[w][2][m * 16 + la];
    float mx = fmaxf(s0, fmaxf(s1, s2));
    float e0 = __expf(s0 - mx), e1 = __expf(s1 - mx), e2 = __expf(s2 - mx);
    float inv = 1.0f / (e0 + e1 + e2);
    float a0 = e0 * inv, a1 = e1 * inv, a2 = e2 * inv;
#pragma unroll
    for (int ks = 0; ks < 4; ++ks) {
      unsigned int ow[4];
#pragma unroll
      for (int jj = 0; jj < 4; ++jj) {
        float v0 = a0 * b2f(a[0][m][ks][2 * jj]) + a1 * b2f(a[1][m][ks][2 * jj]) +
                   a2 * b2f(a[2][m][ks][2 * jj]);
        float v1 = a0 * b2f(a[0][m][ks][2 * jj + 1]) + a1 * b2f(a[1][m][ks][2 * jj + 1]) +
                   a2 * b2f(a[2][m][ks][2 * jj + 1]);
        ow[jj] = (unsigned int)f2bf(v0) | ((unsigned int)f2bf(v1) << 16);
      }
      *(uint4*)(houtb + (size_t)row * DD + gr * 8 + ks * 32) =
          make_uint4(ow[0], ow[1], ow[2], ow[3]);
    }
    if (attn_out != nullptr) {
      attn_out[(size_t)row * 3 + 0] = a0;
      attn_out[(size_t)row * 3 + 1] = a1;
      attn_out[(size_t)row * 3 + 2] = a2;
    }
  }
}

extern "C" void kernel_launch(void* const* d_in, const int* in_sizes, int n_in,
                              void* d_out, int out_size, void* d_ws, size_t ws_size,
                              hipStream_t stream) {
  const float* x        = (const float*)d_in[0];
  const int*   edges    = (const int*)d_in[1];
  const float* feat_w   = (const float*)d_in[2];
  const float* conv_w   = (const float*)d_in[3];
  const float* conv_b   = (const float*)d_in[4];
  const float* attn_w   = (const float*)d_in[5];
  const float* attn_q   = (const float*)d_in[6];
  const float* concat_w = (const float*)d_in[7];
  float* out = (float*)d_out;   // [NN*128 y][NN*3 attn]

  float* ws = (float*)d_ws;
  float* rsqo = ws;                   // [3][NN]
  float* rsqi = rsqo + 3 * NN;        // [3][NN]
  int* btot = (int*)(rsqi + 3 * NN);  // 80 ints
  int* boff = btot + 80;              // 80 ints (unused; layout kept)
  int* cnt = boff + 96;               // spare region; fw overlays here
  int* rowptr = cnt + 3 * NN;         // [3][NN+1] (+pad)
  int* col = rowptr + 3 * (NN + 1) + 13;  // [3][NE]
  const size_t ND = (size_t)NN * DD;
  float* P1 = (float*)(col + 3 * (size_t)NE);  // prologue: rank8 | VbAll 0-1
  float* PA = P1 + ND;   // prologue: hist | VbAll planes 2-3
  float* PB = PA + ND;   // prologue: delta8 | VbAll planes 4-5
  unsigned short* U0 = (unsigned short*)(PB + ND);  // u bf16 x3; later h2b
  unsigned short* B0 = U0 + 3 * ND;   // h0b
  unsigned short* B1 = B0 + ND;       // h1b
  unsigned short* B2 = B1 + ND;       // tb
  unsigned short* fw = (unsigned short*)cnt;   // 10x16384 + 2x8192 ushort
  unsigned int* hist = (unsigned int*)PA;      // [6][NB][NWW] = 12.6 MB <= plane
  unsigned char* delta8 = (unsigned char*)PB;  // [3][NB][NN] = 6.3 MB <= plane
  unsigned char* rank8 = (unsigned char*)P1;   // [3][NE] = 2.4 MB <= plane
  unsigned short* VbAll = (unsigned short*)P1; // 6 bf16 vals planes (contig)
  unsigned short* fa0 = fw + (size_t)10 * 16384;
  unsigned short* fa1 = fa0 + 8192;

  // prologue: histograms + weight prep in one launch; scan; bases(+scanp2);
  // fill + feat GEMM in one launch.
  hist6_kernel<<<dim3(NB, 7), 512, 0, stream>>>(
      edges, hist, rank8, conv_w, feat_w, concat_w, attn_w, fw);
  sumscan_kernel<<<dim3(25, 6), 256, 0, stream>>>(hist, rowptr, btot, rsqi, rsqo);
  bases_kernel<<<dim3(25, 3), 256, 0, stream>>>(hist, btot, rowptr, (unsigned int*)delta8);
  fillfeat_kernel<<<dim3(3125, 4), 256, 0, stream>>>(
      edges, rank8, delta8, rowptr, col, x, fw + (size_t)6 * 16384, B0);

  // shared u[r] = A_r^T (h0 * rsqo_r) -> U planes, batched
  gatherb_kernel<<<dim3(3125, 3), 256, 0, stream>>>(B0, rowptr, col, rsqo, U0);

  // both h0-fed layers in one launch: planes 0-2 = l1 vals, 3-5 = l0 vals
  mgemm_kernel<0, 0, 1, 1><<<dim3(391, 6), 256, 0, stream>>>(
      U0, fw, rsqi, conv_b, B0, VbAll);
  // both mscombs in one launch: h1 -> B1, t -> B2
  mscomb_kernel<1><<<dim3(391, 2), 256, 0, stream>>>(
      VbAll, fa0, attn_q, B1, nullptr);

  // layer l=1 on t: gathers from B2 -> U; convs (resid = B2) -> planes 0-2
  gatherb_kernel<<<dim3(3125, 3), 256, 0, stream>>>(B2, rowptr, col, rsqo, U0);
  mgemm_kernel<0, 0, 1, 0><<<dim3(391, 3), 256, 0, stream>>>(
      U0, fw + (size_t)3 * 16384, rsqi, conv_b + (size_t)3 * DD, B2, VbAll);
  // h2 -> U0 (bf16), attn -> out+ND
  mscomb_kernel<0><<<dim3(391, 1), 256, 0, stream>>>(
      VbAll, fa1, attn_q + DQ, U0, out + ND);

  // y = [h0|h1|h2] @ CW^T -> out
  mconcat_kernel<<<196, 512, 0, stream>>>(B0, B1, U0, fw + (size_t)7 * 16384, out);
}